// Round 3
// baseline (815.355 us; speedup 1.0000x reference)
//
#include <hip/hip_runtime.h>

typedef __attribute__((__ext_vector_type__(8))) __bf16 bf16x8;
typedef __attribute__((__ext_vector_type__(4))) float f32x4;
typedef __attribute__((__ext_vector_type__(4))) unsigned int u32x4;

__device__ __forceinline__ float bf2f(unsigned short u) {
    return __uint_as_float(((unsigned int)u) << 16);
}
__device__ __forceinline__ unsigned short f2bf(float f) {
    unsigned int u = __float_as_uint(f);
    u += 0x7FFFu + ((u >> 16) & 1u);   // RNE
    return (unsigned short)(u >> 16);
}

// ---------------------------------------------------------------------------
// Runtime dtype detector (fixed). Discriminates fp32 vs bf16 storage via the
// LOW 16 bits of each 32-bit word: in a bf16 buffer that's a real bf16 value
// (exponent field in a narrow band, or exact zero); in an fp32 buffer it's
// uniform mantissa bits (in-band with p~0.13). 64-lane majority vote.
// flags[0]=x is fp32, flags[1]=weights are fp32, flags[2]=edges are int64.
// ---------------------------------------------------------------------------
__device__ __forceinline__ bool low_short_is_bf16like(unsigned int w) {
    unsigned int lo = w & 0xFFFFu;
    if (lo == 0u || lo == 0x8000u) return true;          // +/- zero
    unsigned int e = (lo >> 7) & 0xFFu;                  // bf16 exponent field
    return (e >= 0x6Cu && e <= 0x8Cu);                   // |v| in ~[2^-19, 2^13]
}

__global__ __launch_bounds__(64) void k_detect(
    const unsigned int* __restrict__ x, const unsigned int* __restrict__ wl,
    const unsigned int* __restrict__ ei, int* __restrict__ flags)
{
    int t = threadIdx.x;
    int xv = __popcll(__ballot(low_short_is_bf16like(x[t])));
    int wv = __popcll(__ballot(low_short_is_bf16like(wl[t])));
    unsigned int o1 = ei[2 * t + 1];
    unsigned int o2 = ei[2 * t + 129];
    bool oddzero = (o1 == 0u) && (o2 == 0u);
    int e64 = __all(oddzero) ? 1 : 0;
    if (t == 0) {
        flags[0] = (xv < 32) ? 1 : 0;   // few bf16-like low-shorts -> fp32
        flags[1] = (wv < 32) ? 1 : 0;
        flags[2] = e64;
    }
}

// ---------------------------------------------------------------------------
// Weight folding: pack W into [kb][col][8] (kb = k/8) bf16 so MFMA B-frags are
// contiguous 16B. Layer-0 weights absorb the BN affine.
// ---------------------------------------------------------------------------
__global__ __launch_bounds__(256) void k_fold1(
    const void* __restrict__ Wl, const void* __restrict__ Wr,
    const void* __restrict__ Wsk, const void* __restrict__ gamma,
    const void* __restrict__ rvar, const int* __restrict__ flags,
    unsigned short* __restrict__ W1p)
{
    int wf32 = flags[1];
    int idx = blockIdx.x * 256 + threadIdx.x;      // < 32768 = 32kb*128c*8
    int kb = idx >> 10;
    int c  = (idx >> 3) & 127;
    int k7 = idx & 7;
    int k  = kb * 8 + k7;
    float g, rv, w;
    if (wf32) {
        g  = ((const float*)gamma)[c];
        rv = ((const float*)rvar)[c];
        if (k < 128) w = ((const float*)Wl)[k * 128 + c];
        else { int kk = k - 128;
               w = ((const float*)Wr)[kk * 128 + c] + ((const float*)Wsk)[kk * 128 + c]; }
    } else {
        g  = bf2f(((const unsigned short*)gamma)[c]);
        rv = bf2f(((const unsigned short*)rvar)[c]);
        if (k < 128) w = bf2f(((const unsigned short*)Wl)[k * 128 + c]);
        else { int kk = k - 128;
               w = bf2f(((const unsigned short*)Wr)[kk * 128 + c]) +
                   bf2f(((const unsigned short*)Wsk)[kk * 128 + c]); }
    }
    float s = g * rsqrtf(rv + 1e-5f);
    W1p[idx] = f2bf(w * s);
}

__global__ __launch_bounds__(256) void k_fold2(
    const void* __restrict__ Wlo, const void* __restrict__ Wro,
    const int* __restrict__ flags, unsigned short* __restrict__ W2p)
{
    int wf32 = flags[1];
    int idx = blockIdx.x * 256 + threadIdx.x;      // < 81920 = 32kb*320c*8
    int kb  = idx / 2560;
    int rem = idx - kb * 2560;
    int c   = rem >> 3;
    int k7  = idx & 7;
    int k   = kb * 8 + k7;
    float w = 0.f;
    if (c < 300) {
        if (wf32)
            w = (k < 128) ? ((const float*)Wlo)[k * 300 + c]
                          : ((const float*)Wro)[(k - 128) * 300 + c];
        else
            w = (k < 128) ? bf2f(((const unsigned short*)Wlo)[k * 300 + c])
                          : bf2f(((const unsigned short*)Wro)[(k - 128) * 300 + c]);
    }
    W2p[idx] = f2bf(w);
}

__global__ __launch_bounds__(512) void k_foldb(
    const void* __restrict__ bl, const void* __restrict__ bsk,
    const void* __restrict__ rmean, const void* __restrict__ beta,
    const void* __restrict__ gamma, const void* __restrict__ rvar,
    const void* __restrict__ blo, const int* __restrict__ flags,
    float* __restrict__ bias1, float* __restrict__ bias2)
{
    int wf32 = flags[1];
    int t = threadIdx.x;
    if (t < 128) {
        float g, rv, b1, b2, rm, be;
        if (wf32) {
            g = ((const float*)gamma)[t]; rv = ((const float*)rvar)[t];
            b1 = ((const float*)bl)[t];   b2 = ((const float*)bsk)[t];
            rm = ((const float*)rmean)[t]; be = ((const float*)beta)[t];
        } else {
            g = bf2f(((const unsigned short*)gamma)[t]); rv = bf2f(((const unsigned short*)rvar)[t]);
            b1 = bf2f(((const unsigned short*)bl)[t]);   b2 = bf2f(((const unsigned short*)bsk)[t]);
            rm = bf2f(((const unsigned short*)rmean)[t]); be = bf2f(((const unsigned short*)beta)[t]);
        }
        float s = g * rsqrtf(rv + 1e-5f);
        bias1[t] = (b1 + b2 - rm) * s + be;
    } else if (t < 448) {
        int c = t - 128;
        float b = 0.f;
        if (c < 300)
            b = wf32 ? ((const float*)blo)[c] : bf2f(((const unsigned short*)blo)[c]);
        bias2[c] = b;
    }
}

// ---------------------------------------------------------------------------
// Edge-parallel scatter-add: one thread per (edge, channel). fp32 atomics into
// agg[N,128]; DOCNT also builds the in-degree.
// ---------------------------------------------------------------------------
template <int DOCNT, int XDET>
__global__ __launch_bounds__(256) void k_scatter(
    const void* __restrict__ xv, const int* __restrict__ ei,
    const int* __restrict__ flags,
    float* __restrict__ agg, float* __restrict__ cnt, long total, int E, int nnodes)
{
    int xf32 = XDET ? flags[0] : 0;
    int e64  = flags[2];
    const float*          xF = (const float*)xv;
    const unsigned short* xB = (const unsigned short*)xv;
    long stride = (long)gridDim.x * 256;
    for (long t = (long)blockIdx.x * 256 + threadIdx.x; t < total; t += stride) {
        int e = (int)(t >> 7);
        int c = (int)(t & 127);
        int s, d;
        if (e64) { s = ei[2 * e]; d = ei[2 * (E + e)]; }
        else     { s = ei[e];     d = ei[E + e]; }
        if ((unsigned)s >= (unsigned)nnodes || (unsigned)d >= (unsigned)nnodes) continue;
        float v = xf32 ? xF[(long)s * 128 + c] : bf2f(xB[(long)s * 128 + c]);
        unsafeAtomicAdd(&agg[(long)d * 128 + c], v);
        if (DOCNT && c == 0) unsafeAtomicAdd(&cnt[d], 1.0f);
    }
}

// ---------------------------------------------------------------------------
// GEMM1: h = [mean | x] (32x256 tile) @ W1p (256x128) + bias1.
// Writes h (fp32 or bf16 per flags[0]) and relu(h) as internal bf16 xemb.
// ---------------------------------------------------------------------------
__global__ __launch_bounds__(256) void k_gemm1(
    const float* __restrict__ agg, const float* __restrict__ cnt,
    const void* __restrict__ xv, const int* __restrict__ flags,
    const unsigned short* __restrict__ Wp,
    const float* __restrict__ bias, void* __restrict__ outh,
    unsigned short* __restrict__ xemb, int nrows)
{
    constexpr int BN = 128, NTW = 2;
    __shared__ __align__(16) unsigned short Alds[32 * 264];   // +8 pad
    __shared__ __align__(16) unsigned short Blds[4 * BN * 8];
    int tid = threadIdx.x;
    int row0 = blockIdx.x * 32;
    int xf32 = flags[0];
    {   // stage A: cols 0..127 = mean, 128..255 = x
        int r = tid >> 3, c0 = (tid & 7) * 16;
        int rg = row0 + r; if (rg >= nrows) rg = nrows - 1;
        float inv = 1.f / fmaxf(cnt[rg], 1.f);
        const float* ap = agg + (size_t)rg * 128 + c0;
        #pragma unroll
        for (int i = 0; i < 8; i++) {
            unsigned int p = (unsigned int)f2bf(ap[2*i] * inv) |
                             ((unsigned int)f2bf(ap[2*i+1] * inv) << 16);
            *(unsigned int*)&Alds[r * 264 + c0 + 2*i] = p;
        }
        if (xf32) {
            const float* xp = (const float*)xv + (size_t)rg * 128 + c0;
            #pragma unroll
            for (int i = 0; i < 8; i++) {
                unsigned int p = (unsigned int)f2bf(xp[2*i]) |
                                 ((unsigned int)f2bf(xp[2*i+1]) << 16);
                *(unsigned int*)&Alds[r * 264 + 128 + c0 + 2*i] = p;
            }
        } else {
            const u32x4* xp = (const u32x4*)((const unsigned short*)xv + (size_t)rg * 128 + c0);
            *(u32x4*)&Alds[r * 264 + 128 + c0]     = xp[0];
            *(u32x4*)&Alds[r * 264 + 128 + c0 + 8] = xp[1];
        }
    }
    f32x4 acc[2][NTW];
    #pragma unroll
    for (int a = 0; a < 2; a++)
        #pragma unroll
        for (int b = 0; b < NTW; b++) acc[a][b] = f32x4{0.f, 0.f, 0.f, 0.f};
    int lane = tid & 63, wv = tid >> 6, lh = lane & 15, lq = lane >> 4;
    for (int ks = 0; ks < 8; ++ks) {
        __syncthreads();
        const unsigned short* wsrc = Wp + ks * (4 * BN * 8);
        #pragma unroll
        for (int i = 0; i < (4 * BN) / 256; i++) {
            int ch = i * 256 + tid;
            *(u32x4*)&Blds[ch * 8] = *(const u32x4*)&wsrc[ch * 8];
        }
        __syncthreads();
        bf16x8 a0 = *(const bf16x8*)&Alds[lh * 264 + ks * 32 + lq * 8];
        bf16x8 a1 = *(const bf16x8*)&Alds[(16 + lh) * 264 + ks * 32 + lq * 8];
        #pragma unroll
        for (int i = 0; i < NTW; i++) {
            int col = (wv + 4 * i) * 16 + lh;
            bf16x8 bfr = *(const bf16x8*)&Blds[(lq * BN + col) * 8];
            acc[0][i] = __builtin_amdgcn_mfma_f32_16x16x32_bf16(a0, bfr, acc[0][i], 0, 0, 0);
            acc[1][i] = __builtin_amdgcn_mfma_f32_16x16x32_bf16(a1, bfr, acc[1][i], 0, 0, 0);
        }
    }
    float* outF = (float*)outh;
    unsigned short* outB = (unsigned short*)outh;
    #pragma unroll
    for (int rt = 0; rt < 2; ++rt)
        #pragma unroll
        for (int i = 0; i < NTW; i++)
            #pragma unroll
            for (int j = 0; j < 4; j++) {
                int r = row0 + rt * 16 + lq * 4 + j;
                if (r < nrows) {
                    int c = (wv + 4 * i) * 16 + lh;
                    float v = acc[rt][i][j] + bias[c];
                    if (xf32) outF[(size_t)r * 128 + c] = v;
                    else      outB[(size_t)r * 128 + c] = f2bf(v);
                    xemb[(size_t)r * 128 + c] = f2bf(fmaxf(v, 0.f));
                }
            }
}

// ---------------------------------------------------------------------------
// GEMM2 + fused log_softmax: [mean2 | xemb] (32x256) @ W2p (256x320) + blo,
// per-row logsumexp over cols<300 in LDS; output dtype per flags[0].
// ---------------------------------------------------------------------------
__global__ __launch_bounds__(256) void k_gemm2(
    const float* __restrict__ agg, const float* __restrict__ cnt,
    const unsigned short* __restrict__ xf, const unsigned short* __restrict__ Wp,
    const float* __restrict__ bias, const int* __restrict__ flags,
    void* __restrict__ outbase, int nrows)
{
    constexpr int BN = 320, NTW = 5;
    __shared__ __align__(16) char smem[41216];
    unsigned short* Alds = (unsigned short*)smem;             // 16896 B
    unsigned short* Blds = (unsigned short*)(smem + 16896);   // 20480 B
    float* outT = (float*)smem;                               // 32*321*4 = 41088 B (aliased)
    float* Lbuf = (float*)(smem + 41088);                     // 128 B
    int tid = threadIdx.x;
    int row0 = blockIdx.x * 32;
    int xf32 = flags[0];
    {
        int r = tid >> 3, c0 = (tid & 7) * 16;
        int rg = row0 + r; if (rg >= nrows) rg = nrows - 1;
        float inv = 1.f / fmaxf(cnt[rg], 1.f);
        const float* ap = agg + (size_t)rg * 128 + c0;
        #pragma unroll
        for (int i = 0; i < 8; i++) {
            unsigned int p = (unsigned int)f2bf(ap[2*i] * inv) |
                             ((unsigned int)f2bf(ap[2*i+1] * inv) << 16);
            *(unsigned int*)&Alds[r * 264 + c0 + 2*i] = p;
        }
        const u32x4* xp = (const u32x4*)(xf + (size_t)rg * 128 + c0);
        *(u32x4*)&Alds[r * 264 + 128 + c0]     = xp[0];
        *(u32x4*)&Alds[r * 264 + 128 + c0 + 8] = xp[1];
    }
    f32x4 acc[2][NTW];
    #pragma unroll
    for (int a = 0; a < 2; a++)
        #pragma unroll
        for (int b = 0; b < NTW; b++) acc[a][b] = f32x4{0.f, 0.f, 0.f, 0.f};
    int lane = tid & 63, wv = tid >> 6, lh = lane & 15, lq = lane >> 4;
    for (int ks = 0; ks < 8; ++ks) {
        __syncthreads();
        const unsigned short* wsrc = Wp + ks * (4 * BN * 8);
        #pragma unroll
        for (int i = 0; i < (4 * BN) / 256; i++) {
            int ch = i * 256 + tid;
            *(u32x4*)&Blds[ch * 8] = *(const u32x4*)&wsrc[ch * 8];
        }
        __syncthreads();
        bf16x8 a0 = *(const bf16x8*)&Alds[lh * 264 + ks * 32 + lq * 8];
        bf16x8 a1 = *(const bf16x8*)&Alds[(16 + lh) * 264 + ks * 32 + lq * 8];
        #pragma unroll
        for (int i = 0; i < NTW; i++) {
            int col = (wv + 4 * i) * 16 + lh;
            bf16x8 bfr = *(const bf16x8*)&Blds[(lq * BN + col) * 8];
            acc[0][i] = __builtin_amdgcn_mfma_f32_16x16x32_bf16(a0, bfr, acc[0][i], 0, 0, 0);
            acc[1][i] = __builtin_amdgcn_mfma_f32_16x16x32_bf16(a1, bfr, acc[1][i], 0, 0, 0);
        }
    }
    __syncthreads();   // all LDS reads done before aliasing as outT
    #pragma unroll
    for (int rt = 0; rt < 2; ++rt)
        #pragma unroll
        for (int i = 0; i < NTW; i++)
            #pragma unroll
            for (int j = 0; j < 4; j++) {
                int rl = rt * 16 + lq * 4 + j;
                int c  = (wv + 4 * i) * 16 + lh;
                outT[rl * 321 + c] = acc[rt][i][j] + bias[c];
            }
    __syncthreads();
    {   // per-row logsumexp over cols<300; 8 threads per row
        int r = tid >> 3, g = tid & 7;
        float m = -1e30f;
        for (int c = g; c < 300; c += 8) m = fmaxf(m, outT[r * 321 + c]);
        m = fmaxf(m, __shfl_xor(m, 1, 8));
        m = fmaxf(m, __shfl_xor(m, 2, 8));
        m = fmaxf(m, __shfl_xor(m, 4, 8));
        float s = 0.f;
        for (int c = g; c < 300; c += 8) s += __expf(outT[r * 321 + c] - m);
        s += __shfl_xor(s, 1, 8);
        s += __shfl_xor(s, 2, 8);
        s += __shfl_xor(s, 4, 8);
        if (g == 0) Lbuf[r] = m + __logf(s);
    }
    __syncthreads();
    float* out1F = (float*)outbase + (size_t)nrows * 128;
    unsigned short* out1B = (unsigned short*)outbase + (size_t)nrows * 128;
    for (int i = tid; i < 32 * 300; i += 256) {
        int r = i / 300, c = i - r * 300;
        int rg = row0 + r;
        if (rg < nrows) {
            float v = outT[r * 321 + c] - Lbuf[r];
            if (xf32) out1F[(size_t)rg * 300 + c] = v;
            else      out1B[(size_t)rg * 300 + c] = f2bf(v);
        }
    }
}

// ---------------------------------------------------------------------------
extern "C" void kernel_launch(void* const* d_in, const int* in_sizes, int n_in,
                              void* d_out, int out_size, void* d_ws, size_t ws_size,
                              hipStream_t stream)
{
    const void* x     = d_in[0];
    const int*  ei    = (const int*)d_in[1];
    const void* Wl    = d_in[2];
    const void* bl    = d_in[3];
    const void* Wr    = d_in[4];
    const void* Wsk   = d_in[5];
    const void* bsk   = d_in[6];
    const void* gamma = d_in[7];
    const void* beta  = d_in[8];
    const void* rmean = d_in[9];
    const void* rvar  = d_in[10];
    const void* Wlo   = d_in[11];
    const void* blo   = d_in[12];
    const void* Wro   = d_in[13];

    int N = in_sizes[0] / 128;
    int E = in_sizes[1] / 2;

    char* ws = (char*)d_ws;
    size_t off = 0;
    int* flags = (int*)(ws + off);            off += 256;
    float* agg = (float*)(ws + off);          off += (size_t)N * 128 * 4;
    float* cnt = (float*)(ws + off);          off += (size_t)N * 4;
    off = (off + 255) & ~(size_t)255;
    unsigned short* xemb = (unsigned short*)(ws + off); off += (size_t)N * 128 * 2;
    off = (off + 255) & ~(size_t)255;
    unsigned short* W1p = (unsigned short*)(ws + off);  off += 32768 * 2;
    unsigned short* W2p = (unsigned short*)(ws + off);  off += 81920 * 2;
    float* bias1 = (float*)(ws + off);        off += 512;
    float* bias2 = (float*)(ws + off);        off += 1280;

    long total = (long)E * 128;
    int sgrid = 8192;
    int ggrid = (N + 31) / 32;

    hipMemsetAsync(agg, 0, (size_t)N * 128 * 4, stream);
    hipMemsetAsync(cnt, 0, (size_t)N * 4, stream);
    k_detect<<<1, 64, 0, stream>>>((const unsigned int*)x, (const unsigned int*)Wl,
                                   (const unsigned int*)ei, flags);
    k_fold1<<<128, 256, 0, stream>>>(Wl, Wr, Wsk, gamma, rvar, flags, W1p);
    k_fold2<<<320, 256, 0, stream>>>(Wlo, Wro, flags, W2p);
    k_foldb<<<1, 512, 0, stream>>>(bl, bsk, rmean, beta, gamma, rvar, blo, flags, bias1, bias2);

    k_scatter<1, 1><<<sgrid, 256, 0, stream>>>(x, ei, flags, agg, cnt, total, E, N);
    k_gemm1<<<ggrid, 256, 0, stream>>>(agg, cnt, x, flags, W1p, bias1, d_out, xemb, N);

    hipMemsetAsync(agg, 0, (size_t)N * 128 * 4, stream);
    k_scatter<0, 0><<<sgrid, 256, 0, stream>>>(xemb, ei, flags, agg, cnt, total, E, N);
    k_gemm2<<<ggrid, 256, 0, stream>>>(agg, cnt, xemb, W2p, bias2, flags, d_out, N);
}

// Round 4
// 296.057 us; speedup vs baseline: 2.7540x; 2.7540x over previous
//
#include <hip/hip_runtime.h>

typedef __attribute__((__ext_vector_type__(8))) __bf16 bf16x8;
typedef __attribute__((__ext_vector_type__(4))) float f32x4;
typedef __attribute__((__ext_vector_type__(4))) unsigned int u32x4;

__device__ __forceinline__ float bf2f(unsigned short u) {
    return __uint_as_float(((unsigned int)u) << 16);
}
__device__ __forceinline__ unsigned short f2bf(float f) {
    unsigned int u = __float_as_uint(f);
    u += 0x7FFFu + ((u >> 16) & 1u);   // RNE
    return (unsigned short)(u >> 16);
}

// ---------------------------------------------------------------------------
// Runtime dtype detector (validated in round 3). flags[0]=x fp32,
// flags[1]=weights fp32, flags[2]=edges int64.
// ---------------------------------------------------------------------------
__device__ __forceinline__ bool low_short_is_bf16like(unsigned int w) {
    unsigned int lo = w & 0xFFFFu;
    if (lo == 0u || lo == 0x8000u) return true;
    unsigned int e = (lo >> 7) & 0xFFu;
    return (e >= 0x6Cu && e <= 0x8Cu);
}

__global__ __launch_bounds__(64) void k_detect(
    const unsigned int* __restrict__ x, const unsigned int* __restrict__ wl,
    const unsigned int* __restrict__ ei, int* __restrict__ flags)
{
    int t = threadIdx.x;
    int xv = __popcll(__ballot(low_short_is_bf16like(x[t])));
    int wv = __popcll(__ballot(low_short_is_bf16like(wl[t])));
    unsigned int o1 = ei[2 * t + 1];
    unsigned int o2 = ei[2 * t + 129];
    bool oddzero = (o1 == 0u) && (o2 == 0u);
    int e64 = __all(oddzero) ? 1 : 0;
    if (t == 0) {
        flags[0] = (xv < 32) ? 1 : 0;
        flags[1] = (wv < 32) ? 1 : 0;
        flags[2] = e64;
    }
}

// ---------------------------------------------------------------------------
// Weight folding (unchanged from round 3).
// ---------------------------------------------------------------------------
__global__ __launch_bounds__(256) void k_fold1(
    const void* __restrict__ Wl, const void* __restrict__ Wr,
    const void* __restrict__ Wsk, const void* __restrict__ gamma,
    const void* __restrict__ rvar, const int* __restrict__ flags,
    unsigned short* __restrict__ W1p)
{
    int wf32 = flags[1];
    int idx = blockIdx.x * 256 + threadIdx.x;
    int kb = idx >> 10;
    int c  = (idx >> 3) & 127;
    int k7 = idx & 7;
    int k  = kb * 8 + k7;
    float g, rv, w;
    if (wf32) {
        g  = ((const float*)gamma)[c];
        rv = ((const float*)rvar)[c];
        if (k < 128) w = ((const float*)Wl)[k * 128 + c];
        else { int kk = k - 128;
               w = ((const float*)Wr)[kk * 128 + c] + ((const float*)Wsk)[kk * 128 + c]; }
    } else {
        g  = bf2f(((const unsigned short*)gamma)[c]);
        rv = bf2f(((const unsigned short*)rvar)[c]);
        if (k < 128) w = bf2f(((const unsigned short*)Wl)[k * 128 + c]);
        else { int kk = k - 128;
               w = bf2f(((const unsigned short*)Wr)[kk * 128 + c]) +
                   bf2f(((const unsigned short*)Wsk)[kk * 128 + c]); }
    }
    float s = g * rsqrtf(rv + 1e-5f);
    W1p[idx] = f2bf(w * s);
}

__global__ __launch_bounds__(256) void k_fold2(
    const void* __restrict__ Wlo, const void* __restrict__ Wro,
    const int* __restrict__ flags, unsigned short* __restrict__ W2p)
{
    int wf32 = flags[1];
    int idx = blockIdx.x * 256 + threadIdx.x;
    int kb  = idx / 2560;
    int rem = idx - kb * 2560;
    int c   = rem >> 3;
    int k7  = idx & 7;
    int k   = kb * 8 + k7;
    float w = 0.f;
    if (c < 300) {
        if (wf32)
            w = (k < 128) ? ((const float*)Wlo)[k * 300 + c]
                          : ((const float*)Wro)[(k - 128) * 300 + c];
        else
            w = (k < 128) ? bf2f(((const unsigned short*)Wlo)[k * 300 + c])
                          : bf2f(((const unsigned short*)Wro)[(k - 128) * 300 + c]);
    }
    W2p[idx] = f2bf(w);
}

__global__ __launch_bounds__(512) void k_foldb(
    const void* __restrict__ bl, const void* __restrict__ bsk,
    const void* __restrict__ rmean, const void* __restrict__ beta,
    const void* __restrict__ gamma, const void* __restrict__ rvar,
    const void* __restrict__ blo, const int* __restrict__ flags,
    float* __restrict__ bias1, float* __restrict__ bias2)
{
    int wf32 = flags[1];
    int t = threadIdx.x;
    if (t < 128) {
        float g, rv, b1, b2, rm, be;
        if (wf32) {
            g = ((const float*)gamma)[t]; rv = ((const float*)rvar)[t];
            b1 = ((const float*)bl)[t];   b2 = ((const float*)bsk)[t];
            rm = ((const float*)rmean)[t]; be = ((const float*)beta)[t];
        } else {
            g = bf2f(((const unsigned short*)gamma)[t]); rv = bf2f(((const unsigned short*)rvar)[t]);
            b1 = bf2f(((const unsigned short*)bl)[t]);   b2 = bf2f(((const unsigned short*)bsk)[t]);
            rm = bf2f(((const unsigned short*)rmean)[t]); be = bf2f(((const unsigned short*)beta)[t]);
        }
        float s = g * rsqrtf(rv + 1e-5f);
        bias1[t] = (b1 + b2 - rm) * s + be;
    } else if (t < 448) {
        int c = t - 128;
        float b = 0.f;
        if (c < 300)
            b = wf32 ? ((const float*)blo)[c] : bf2f(((const unsigned short*)blo)[c]);
        bias2[c] = b;
    }
}

// ---------------------------------------------------------------------------
// CSR build: histogram -> 3-phase exclusive scan -> fill.
// ---------------------------------------------------------------------------
__global__ __launch_bounds__(256) void k_hist(
    const int* __restrict__ ei, const int* __restrict__ flags,
    int* __restrict__ deg, int E, int nnodes)
{
    int e64 = flags[2];
    int e = blockIdx.x * 256 + threadIdx.x;
    if (e >= E) return;
    int d = e64 ? ei[2 * (E + e)] : ei[E + e];
    if ((unsigned)d < (unsigned)nnodes) atomicAdd(&deg[d], 1);
}

__global__ __launch_bounds__(256) void k_scan_a(
    const int* __restrict__ deg, int* __restrict__ rowptr,
    int* __restrict__ aux, int n)
{
    __shared__ int wsum[4];
    int t = threadIdx.x, blk = blockIdx.x;
    int base = blk * 1024 + t * 4;
    int v[4];
    int s = 0;
    #pragma unroll
    for (int i = 0; i < 4; i++) { int idx = base + i; v[i] = (idx < n) ? deg[idx] : 0; s += v[i]; }
    int lane = t & 63, wv = t >> 6;
    int inc = s;
    #pragma unroll
    for (int off = 1; off < 64; off <<= 1) {
        int u = __shfl_up(inc, off);
        if (lane >= off) inc += u;
    }
    if (lane == 63) wsum[wv] = inc;
    __syncthreads();
    int woff = 0;
    if (wv >= 1) woff += wsum[0];
    if (wv >= 2) woff += wsum[1];
    if (wv >= 3) woff += wsum[2];
    int exc = woff + inc - s;
    #pragma unroll
    for (int i = 0; i < 4; i++) { int idx = base + i; if (idx < n) rowptr[idx] = exc; exc += v[i]; }
    if (t == 255) aux[blk] = woff + inc;
}

__global__ __launch_bounds__(64) void k_scan_b(int* __restrict__ aux, int nblk)
{
    int t = threadIdx.x;
    int v = (t < nblk) ? aux[t] : 0;
    int inc = v;
    #pragma unroll
    for (int off = 1; off < 64; off <<= 1) {
        int u = __shfl_up(inc, off);
        if (t >= off) inc += u;
    }
    if (t < nblk) aux[t] = inc - v;   // exclusive
}

__global__ __launch_bounds__(256) void k_scan_c(
    int* __restrict__ rowptr, int* __restrict__ wofs,
    const int* __restrict__ aux, int n)
{
    int i = blockIdx.x * 256 + threadIdx.x;
    if (i < n) {
        int r = rowptr[i] + aux[i >> 10];
        rowptr[i] = r;
        wofs[i] = r;
    }
}

__global__ __launch_bounds__(256) void k_fill(
    const int* __restrict__ ei, const int* __restrict__ flags,
    int* __restrict__ wofs, int* __restrict__ adj, int E, int nnodes)
{
    int e64 = flags[2];
    int e = blockIdx.x * 256 + threadIdx.x;
    if (e >= E) return;
    int s, d;
    if (e64) { s = ei[2 * e]; d = ei[2 * (E + e)]; }
    else     { s = ei[e];     d = ei[E + e]; }
    if ((unsigned)d >= (unsigned)nnodes) return;
    if ((unsigned)s >= (unsigned)nnodes) s = 0;   // defensive clamp
    int slot = atomicAdd(&wofs[d], 1);
    adj[slot] = s;
}

// ---------------------------------------------------------------------------
// Gather-mean: one wave per dst node; lane owns 2 channels (float2 row loads);
// fp32 accumulate, /deg, write bf16 mean row. No atomics, no zero-init.
// XDET=1: x dtype from flags[0]; XDET=0: bf16 (xemb).
// ---------------------------------------------------------------------------
template <int XDET>
__global__ __launch_bounds__(256) void k_agg(
    const void* __restrict__ xv, const int* __restrict__ flags,
    const int* __restrict__ rowptr, const int* __restrict__ deg,
    const int* __restrict__ adj, unsigned short* __restrict__ meanB, int n)
{
    int wid = (blockIdx.x * 256 + threadIdx.x) >> 6;   // node id
    if (wid >= n) return;
    int lane = threadIdx.x & 63;
    int xf32 = XDET ? flags[0] : 0;
    int start = rowptr[wid], dc = deg[wid];
    float a0 = 0.f, a1 = 0.f, b0 = 0.f, b1 = 0.f;
    if (xf32) {
        const float* xF = (const float*)xv;
        int i = 0;
        for (; i + 1 < dc; i += 2) {
            int s0 = adj[start + i], s1 = adj[start + i + 1];
            float2 v0 = *(const float2*)&xF[(size_t)s0 * 128 + lane * 2];
            float2 v1 = *(const float2*)&xF[(size_t)s1 * 128 + lane * 2];
            a0 += v0.x; a1 += v0.y; b0 += v1.x; b1 += v1.y;
        }
        if (i < dc) {
            int s0 = adj[start + i];
            float2 v0 = *(const float2*)&xF[(size_t)s0 * 128 + lane * 2];
            a0 += v0.x; a1 += v0.y;
        }
    } else {
        const unsigned short* xB = (const unsigned short*)xv;
        int i = 0;
        for (; i + 1 < dc; i += 2) {
            int s0 = adj[start + i], s1 = adj[start + i + 1];
            unsigned int p0 = *(const unsigned int*)&xB[(size_t)s0 * 128 + lane * 2];
            unsigned int p1 = *(const unsigned int*)&xB[(size_t)s1 * 128 + lane * 2];
            a0 += bf2f((unsigned short)p0); a1 += bf2f((unsigned short)(p0 >> 16));
            b0 += bf2f((unsigned short)p1); b1 += bf2f((unsigned short)(p1 >> 16));
        }
        if (i < dc) {
            int s0 = adj[start + i];
            unsigned int p0 = *(const unsigned int*)&xB[(size_t)s0 * 128 + lane * 2];
            a0 += bf2f((unsigned short)p0); a1 += bf2f((unsigned short)(p0 >> 16));
        }
    }
    float inv = 1.f / fmaxf((float)dc, 1.f);
    unsigned int out = (unsigned int)f2bf((a0 + b0) * inv) |
                       ((unsigned int)f2bf((a1 + b1) * inv) << 16);
    *(unsigned int*)&meanB[(size_t)wid * 128 + lane * 2] = out;
}

// ---------------------------------------------------------------------------
// GEMM1: h = [mean | x] (32x256 tile) @ W1p (256x128) + bias1.
// Writes h (fp32 or bf16 per flags[0]) and relu(h) as internal bf16 xemb.
// ---------------------------------------------------------------------------
__global__ __launch_bounds__(256) void k_gemm1(
    const unsigned short* __restrict__ meanB,
    const void* __restrict__ xv, const int* __restrict__ flags,
    const unsigned short* __restrict__ Wp,
    const float* __restrict__ bias, void* __restrict__ outh,
    unsigned short* __restrict__ xemb, int nrows)
{
    constexpr int BN = 128, NTW = 2;
    __shared__ __align__(16) unsigned short Alds[32 * 264];
    __shared__ __align__(16) unsigned short Blds[4 * BN * 8];
    int tid = threadIdx.x;
    int row0 = blockIdx.x * 32;
    int xf32 = flags[0];
    {
        int r = tid >> 3, c0 = (tid & 7) * 16;
        int rg = row0 + r; if (rg >= nrows) rg = nrows - 1;
        const u32x4* mp = (const u32x4*)(meanB + (size_t)rg * 128 + c0);
        *(u32x4*)&Alds[r * 264 + c0]     = mp[0];
        *(u32x4*)&Alds[r * 264 + c0 + 8] = mp[1];
        if (xf32) {
            const float* xp = (const float*)xv + (size_t)rg * 128 + c0;
            #pragma unroll
            for (int i = 0; i < 8; i++) {
                unsigned int p = (unsigned int)f2bf(xp[2*i]) |
                                 ((unsigned int)f2bf(xp[2*i+1]) << 16);
                *(unsigned int*)&Alds[r * 264 + 128 + c0 + 2*i] = p;
            }
        } else {
            const u32x4* xp = (const u32x4*)((const unsigned short*)xv + (size_t)rg * 128 + c0);
            *(u32x4*)&Alds[r * 264 + 128 + c0]     = xp[0];
            *(u32x4*)&Alds[r * 264 + 128 + c0 + 8] = xp[1];
        }
    }
    f32x4 acc[2][NTW];
    #pragma unroll
    for (int a = 0; a < 2; a++)
        #pragma unroll
        for (int b = 0; b < NTW; b++) acc[a][b] = f32x4{0.f, 0.f, 0.f, 0.f};
    int lane = tid & 63, wv = tid >> 6, lh = lane & 15, lq = lane >> 4;
    for (int ks = 0; ks < 8; ++ks) {
        __syncthreads();
        const unsigned short* wsrc = Wp + ks * (4 * BN * 8);
        #pragma unroll
        for (int i = 0; i < (4 * BN) / 256; i++) {
            int ch = i * 256 + tid;
            *(u32x4*)&Blds[ch * 8] = *(const u32x4*)&wsrc[ch * 8];
        }
        __syncthreads();
        bf16x8 a0 = *(const bf16x8*)&Alds[lh * 264 + ks * 32 + lq * 8];
        bf16x8 a1 = *(const bf16x8*)&Alds[(16 + lh) * 264 + ks * 32 + lq * 8];
        #pragma unroll
        for (int i = 0; i < NTW; i++) {
            int col = (wv + 4 * i) * 16 + lh;
            bf16x8 bfr = *(const bf16x8*)&Blds[(lq * BN + col) * 8];
            acc[0][i] = __builtin_amdgcn_mfma_f32_16x16x32_bf16(a0, bfr, acc[0][i], 0, 0, 0);
            acc[1][i] = __builtin_amdgcn_mfma_f32_16x16x32_bf16(a1, bfr, acc[1][i], 0, 0, 0);
        }
    }
    float* outF = (float*)outh;
    unsigned short* outB = (unsigned short*)outh;
    #pragma unroll
    for (int rt = 0; rt < 2; ++rt)
        #pragma unroll
        for (int i = 0; i < NTW; i++)
            #pragma unroll
            for (int j = 0; j < 4; j++) {
                int r = row0 + rt * 16 + lq * 4 + j;
                if (r < nrows) {
                    int c = (wv + 4 * i) * 16 + lh;
                    float v = acc[rt][i][j] + bias[c];
                    if (xf32) outF[(size_t)r * 128 + c] = v;
                    else      outB[(size_t)r * 128 + c] = f2bf(v);
                    xemb[(size_t)r * 128 + c] = f2bf(fmaxf(v, 0.f));
                }
            }
}

// ---------------------------------------------------------------------------
// GEMM2 + fused log_softmax (reads meanB + xemb).
// ---------------------------------------------------------------------------
__global__ __launch_bounds__(256) void k_gemm2(
    const unsigned short* __restrict__ meanB,
    const unsigned short* __restrict__ xf, const unsigned short* __restrict__ Wp,
    const float* __restrict__ bias, const int* __restrict__ flags,
    void* __restrict__ outbase, int nrows)
{
    constexpr int BN = 320, NTW = 5;
    __shared__ __align__(16) char smem[41216];
    unsigned short* Alds = (unsigned short*)smem;
    unsigned short* Blds = (unsigned short*)(smem + 16896);
    float* outT = (float*)smem;
    float* Lbuf = (float*)(smem + 41088);
    int tid = threadIdx.x;
    int row0 = blockIdx.x * 32;
    int xf32 = flags[0];
    {
        int r = tid >> 3, c0 = (tid & 7) * 16;
        int rg = row0 + r; if (rg >= nrows) rg = nrows - 1;
        const u32x4* mp = (const u32x4*)(meanB + (size_t)rg * 128 + c0);
        *(u32x4*)&Alds[r * 264 + c0]     = mp[0];
        *(u32x4*)&Alds[r * 264 + c0 + 8] = mp[1];
        const u32x4* xp = (const u32x4*)(xf + (size_t)rg * 128 + c0);
        *(u32x4*)&Alds[r * 264 + 128 + c0]     = xp[0];
        *(u32x4*)&Alds[r * 264 + 128 + c0 + 8] = xp[1];
    }
    f32x4 acc[2][NTW];
    #pragma unroll
    for (int a = 0; a < 2; a++)
        #pragma unroll
        for (int b = 0; b < NTW; b++) acc[a][b] = f32x4{0.f, 0.f, 0.f, 0.f};
    int lane = tid & 63, wv = tid >> 6, lh = lane & 15, lq = lane >> 4;
    for (int ks = 0; ks < 8; ++ks) {
        __syncthreads();
        const unsigned short* wsrc = Wp + ks * (4 * BN * 8);
        #pragma unroll
        for (int i = 0; i < (4 * BN) / 256; i++) {
            int ch = i * 256 + tid;
            *(u32x4*)&Blds[ch * 8] = *(const u32x4*)&wsrc[ch * 8];
        }
        __syncthreads();
        bf16x8 a0 = *(const bf16x8*)&Alds[lh * 264 + ks * 32 + lq * 8];
        bf16x8 a1 = *(const bf16x8*)&Alds[(16 + lh) * 264 + ks * 32 + lq * 8];
        #pragma unroll
        for (int i = 0; i < NTW; i++) {
            int col = (wv + 4 * i) * 16 + lh;
            bf16x8 bfr = *(const bf16x8*)&Blds[(lq * BN + col) * 8];
            acc[0][i] = __builtin_amdgcn_mfma_f32_16x16x32_bf16(a0, bfr, acc[0][i], 0, 0, 0);
            acc[1][i] = __builtin_amdgcn_mfma_f32_16x16x32_bf16(a1, bfr, acc[1][i], 0, 0, 0);
        }
    }
    __syncthreads();
    #pragma unroll
    for (int rt = 0; rt < 2; ++rt)
        #pragma unroll
        for (int i = 0; i < NTW; i++)
            #pragma unroll
            for (int j = 0; j < 4; j++) {
                int rl = rt * 16 + lq * 4 + j;
                int c  = (wv + 4 * i) * 16 + lh;
                outT[rl * 321 + c] = acc[rt][i][j] + bias[c];
            }
    __syncthreads();
    {
        int r = tid >> 3, g = tid & 7;
        float m = -1e30f;
        for (int c = g; c < 300; c += 8) m = fmaxf(m, outT[r * 321 + c]);
        m = fmaxf(m, __shfl_xor(m, 1, 8));
        m = fmaxf(m, __shfl_xor(m, 2, 8));
        m = fmaxf(m, __shfl_xor(m, 4, 8));
        float s = 0.f;
        for (int c = g; c < 300; c += 8) s += __expf(outT[r * 321 + c] - m);
        s += __shfl_xor(s, 1, 8);
        s += __shfl_xor(s, 2, 8);
        s += __shfl_xor(s, 4, 8);
        if (g == 0) Lbuf[r] = m + __logf(s);
    }
    __syncthreads();
    float* out1F = (float*)outbase + (size_t)nrows * 128;
    unsigned short* out1B = (unsigned short*)outbase + (size_t)nrows * 128;
    for (int i = tid; i < 32 * 300; i += 256) {
        int r = i / 300, c = i - r * 300;
        int rg = row0 + r;
        if (rg < nrows) {
            float v = outT[r * 321 + c] - Lbuf[r];
            if (xf32) out1F[(size_t)rg * 300 + c] = v;
            else      out1B[(size_t)rg * 300 + c] = f2bf(v);
        }
    }
}

// ---------------------------------------------------------------------------
extern "C" void kernel_launch(void* const* d_in, const int* in_sizes, int n_in,
                              void* d_out, int out_size, void* d_ws, size_t ws_size,
                              hipStream_t stream)
{
    const void* x     = d_in[0];
    const int*  ei    = (const int*)d_in[1];
    const void* Wl    = d_in[2];
    const void* bl    = d_in[3];
    const void* Wr    = d_in[4];
    const void* Wsk   = d_in[5];
    const void* bsk   = d_in[6];
    const void* gamma = d_in[7];
    const void* beta  = d_in[8];
    const void* rmean = d_in[9];
    const void* rvar  = d_in[10];
    const void* Wlo   = d_in[11];
    const void* blo   = d_in[12];
    const void* Wro   = d_in[13];

    int N = in_sizes[0] / 128;
    int E = in_sizes[1] / 2;

    char* ws = (char*)d_ws;
    size_t off = 0;
    int* flags = (int*)(ws + off);            off += 256;
    unsigned short* meanB = (unsigned short*)(ws + off); off += (size_t)N * 128 * 2;
    unsigned short* xemb  = (unsigned short*)(ws + off); off += (size_t)N * 128 * 2;
    off = (off + 255) & ~(size_t)255;
    int* deg    = (int*)(ws + off);           off += (size_t)N * 4;
    int* rowptr = (int*)(ws + off);           off += (size_t)N * 4;
    int* wofs   = (int*)(ws + off);           off += (size_t)N * 4;
    int* aux    = (int*)(ws + off);           off += 256;
    int* adj    = (int*)(ws + off);           off += (size_t)E * 4;
    off = (off + 255) & ~(size_t)255;
    unsigned short* W1p = (unsigned short*)(ws + off);  off += 32768 * 2;
    unsigned short* W2p = (unsigned short*)(ws + off);  off += 81920 * 2;
    float* bias1 = (float*)(ws + off);        off += 512;
    float* bias2 = (float*)(ws + off);        off += 1280;

    int egrid = (E + 255) / 256;
    int sblk  = (N + 1023) / 1024;            // scan-a blocks (<= 64)
    int cgrid = (N + 255) / 256;
    int agrid = (N + 3) / 4;                  // 4 nodes (waves) per block
    int ggrid = (N + 31) / 32;

    hipMemsetAsync(deg, 0, (size_t)N * 4, stream);
    k_detect<<<1, 64, 0, stream>>>((const unsigned int*)x, (const unsigned int*)Wl,
                                   (const unsigned int*)ei, flags);
    k_fold1<<<128, 256, 0, stream>>>(Wl, Wr, Wsk, gamma, rvar, flags, W1p);
    k_fold2<<<320, 256, 0, stream>>>(Wlo, Wro, flags, W2p);
    k_foldb<<<1, 512, 0, stream>>>(bl, bsk, rmean, beta, gamma, rvar, blo, flags, bias1, bias2);

    // CSR build (shared by both layers)
    k_hist<<<egrid, 256, 0, stream>>>(ei, flags, deg, E, N);
    k_scan_a<<<sblk, 256, 0, stream>>>(deg, rowptr, aux, N);
    k_scan_b<<<1, 64, 0, stream>>>(aux, sblk);
    k_scan_c<<<cgrid, 256, 0, stream>>>(rowptr, wofs, aux, N);
    k_fill<<<egrid, 256, 0, stream>>>(ei, flags, wofs, adj, E, N);

    // layer 0
    k_agg<1><<<agrid, 256, 0, stream>>>(x, flags, rowptr, deg, adj, meanB, N);
    k_gemm1<<<ggrid, 256, 0, stream>>>(meanB, x, flags, W1p, bias1, d_out, xemb, N);

    // layer 1
    k_agg<0><<<agrid, 256, 0, stream>>>(xemb, flags, rowptr, deg, adj, meanB, N);
    k_gemm2<<<ggrid, 256, 0, stream>>>(meanB, xemb, W2p, bias2, flags, d_out, N);
}

// Round 5
// 272.649 us; speedup vs baseline: 2.9905x; 1.0859x over previous
//
#include <hip/hip_runtime.h>

typedef __attribute__((__ext_vector_type__(8))) __bf16 bf16x8;
typedef __attribute__((__ext_vector_type__(4))) float f32x4;
typedef __attribute__((__ext_vector_type__(4))) unsigned int u32x4;

__device__ __forceinline__ float bf2f(unsigned short u) {
    return __uint_as_float(((unsigned int)u) << 16);
}
__device__ __forceinline__ unsigned short f2bf(float f) {
    unsigned int u = __float_as_uint(f);
    u += 0x7FFFu + ((u >> 16) & 1u);   // RNE
    return (unsigned short)(u >> 16);
}

// ---------------------------------------------------------------------------
// Runtime dtype detector (validated round 3/4). flags[0]=x fp32,
// flags[1]=weights fp32, flags[2]=edges int64.
// ---------------------------------------------------------------------------
__device__ __forceinline__ bool low_short_is_bf16like(unsigned int w) {
    unsigned int lo = w & 0xFFFFu;
    if (lo == 0u || lo == 0x8000u) return true;
    unsigned int e = (lo >> 7) & 0xFFu;
    return (e >= 0x6Cu && e <= 0x8Cu);
}

__global__ __launch_bounds__(64) void k_detect(
    const unsigned int* __restrict__ x, const unsigned int* __restrict__ wl,
    const unsigned int* __restrict__ ei, int* __restrict__ flags)
{
    int t = threadIdx.x;
    int xv = __popcll(__ballot(low_short_is_bf16like(x[t])));
    int wv = __popcll(__ballot(low_short_is_bf16like(wl[t])));
    unsigned int o1 = ei[2 * t + 1];
    unsigned int o2 = ei[2 * t + 129];
    bool oddzero = (o1 == 0u) && (o2 == 0u);
    int e64 = __all(oddzero) ? 1 : 0;
    if (t == 0) {
        flags[0] = (xv < 32) ? 1 : 0;
        flags[1] = (wv < 32) ? 1 : 0;
        flags[2] = e64;
    }
}

// ---------------------------------------------------------------------------
// x -> bf16 copy/convert (one pass; both agg layers + GEMM1 consume bf16).
// ---------------------------------------------------------------------------
__global__ __launch_bounds__(256) void k_tobf(
    const void* __restrict__ xv, const int* __restrict__ flags,
    unsigned short* __restrict__ xbf, long nelem)
{
    int xf32 = flags[0];
    long i = ((long)blockIdx.x * 256 + threadIdx.x) * 8;
    if (i >= nelem) return;
    if (xf32) {
        const float4* p = (const float4*)((const float*)xv + i);
        float4 v0 = p[0], v1 = p[1];
        u32x4 o;
        o.x = (unsigned int)f2bf(v0.x) | ((unsigned int)f2bf(v0.y) << 16);
        o.y = (unsigned int)f2bf(v0.z) | ((unsigned int)f2bf(v0.w) << 16);
        o.z = (unsigned int)f2bf(v1.x) | ((unsigned int)f2bf(v1.y) << 16);
        o.w = (unsigned int)f2bf(v1.z) | ((unsigned int)f2bf(v1.w) << 16);
        *(u32x4*)&xbf[i] = o;
    } else {
        *(u32x4*)&xbf[i] = *(const u32x4*)((const unsigned short*)xv + i);
    }
}

// ---------------------------------------------------------------------------
// Weight folding (unchanged).
// ---------------------------------------------------------------------------
__global__ __launch_bounds__(256) void k_fold1(
    const void* __restrict__ Wl, const void* __restrict__ Wr,
    const void* __restrict__ Wsk, const void* __restrict__ gamma,
    const void* __restrict__ rvar, const int* __restrict__ flags,
    unsigned short* __restrict__ W1p)
{
    int wf32 = flags[1];
    int idx = blockIdx.x * 256 + threadIdx.x;
    int kb = idx >> 10;
    int c  = (idx >> 3) & 127;
    int k7 = idx & 7;
    int k  = kb * 8 + k7;
    float g, rv, w;
    if (wf32) {
        g  = ((const float*)gamma)[c];
        rv = ((const float*)rvar)[c];
        if (k < 128) w = ((const float*)Wl)[k * 128 + c];
        else { int kk = k - 128;
               w = ((const float*)Wr)[kk * 128 + c] + ((const float*)Wsk)[kk * 128 + c]; }
    } else {
        g  = bf2f(((const unsigned short*)gamma)[c]);
        rv = bf2f(((const unsigned short*)rvar)[c]);
        if (k < 128) w = bf2f(((const unsigned short*)Wl)[k * 128 + c]);
        else { int kk = k - 128;
               w = bf2f(((const unsigned short*)Wr)[kk * 128 + c]) +
                   bf2f(((const unsigned short*)Wsk)[kk * 128 + c]); }
    }
    float s = g * rsqrtf(rv + 1e-5f);
    W1p[idx] = f2bf(w * s);
}

__global__ __launch_bounds__(256) void k_fold2(
    const void* __restrict__ Wlo, const void* __restrict__ Wro,
    const int* __restrict__ flags, unsigned short* __restrict__ W2p)
{
    int wf32 = flags[1];
    int idx = blockIdx.x * 256 + threadIdx.x;
    int kb  = idx / 2560;
    int rem = idx - kb * 2560;
    int c   = rem >> 3;
    int k7  = idx & 7;
    int k   = kb * 8 + k7;
    float w = 0.f;
    if (c < 300) {
        if (wf32)
            w = (k < 128) ? ((const float*)Wlo)[k * 300 + c]
                          : ((const float*)Wro)[(k - 128) * 300 + c];
        else
            w = (k < 128) ? bf2f(((const unsigned short*)Wlo)[k * 300 + c])
                          : bf2f(((const unsigned short*)Wro)[(k - 128) * 300 + c]);
    }
    W2p[idx] = f2bf(w);
}

__global__ __launch_bounds__(512) void k_foldb(
    const void* __restrict__ bl, const void* __restrict__ bsk,
    const void* __restrict__ rmean, const void* __restrict__ beta,
    const void* __restrict__ gamma, const void* __restrict__ rvar,
    const void* __restrict__ blo, const int* __restrict__ flags,
    float* __restrict__ bias1, float* __restrict__ bias2)
{
    int wf32 = flags[1];
    int t = threadIdx.x;
    if (t < 128) {
        float g, rv, b1, b2, rm, be;
        if (wf32) {
            g = ((const float*)gamma)[t]; rv = ((const float*)rvar)[t];
            b1 = ((const float*)bl)[t];   b2 = ((const float*)bsk)[t];
            rm = ((const float*)rmean)[t]; be = ((const float*)beta)[t];
        } else {
            g = bf2f(((const unsigned short*)gamma)[t]); rv = bf2f(((const unsigned short*)rvar)[t]);
            b1 = bf2f(((const unsigned short*)bl)[t]);   b2 = bf2f(((const unsigned short*)bsk)[t]);
            rm = bf2f(((const unsigned short*)rmean)[t]); be = bf2f(((const unsigned short*)beta)[t]);
        }
        float s = g * rsqrtf(rv + 1e-5f);
        bias1[t] = (b1 + b2 - rm) * s + be;
    } else if (t < 448) {
        int c = t - 128;
        float b = 0.f;
        if (c < 300)
            b = wf32 ? ((const float*)blo)[c] : bf2f(((const unsigned short*)blo)[c]);
        bias2[c] = b;
    }
}

// ---------------------------------------------------------------------------
// CSR build: histogram -> 3-phase exclusive scan -> fill. 4 edges/thread for
// atomic MLP.
// ---------------------------------------------------------------------------
__global__ __launch_bounds__(256) void k_hist(
    const int* __restrict__ ei, const int* __restrict__ flags,
    int* __restrict__ deg, int E, int nnodes)
{
    int e64 = flags[2];
    int base = (blockIdx.x * 256 + threadIdx.x) * 4;
    #pragma unroll
    for (int j = 0; j < 4; j++) {
        int e = base + j;
        if (e >= E) return;
        int d = e64 ? ei[2 * (E + e)] : ei[E + e];
        if ((unsigned)d < (unsigned)nnodes) atomicAdd(&deg[d], 1);
    }
}

__global__ __launch_bounds__(256) void k_scan_a(
    const int* __restrict__ deg, int* __restrict__ rowptr,
    int* __restrict__ aux, int n)
{
    __shared__ int wsum[4];
    int t = threadIdx.x, blk = blockIdx.x;
    int base = blk * 1024 + t * 4;
    int v[4];
    int s = 0;
    #pragma unroll
    for (int i = 0; i < 4; i++) { int idx = base + i; v[i] = (idx < n) ? deg[idx] : 0; s += v[i]; }
    int lane = t & 63, wv = t >> 6;
    int inc = s;
    #pragma unroll
    for (int off = 1; off < 64; off <<= 1) {
        int u = __shfl_up(inc, off);
        if (lane >= off) inc += u;
    }
    if (lane == 63) wsum[wv] = inc;
    __syncthreads();
    int woff = 0;
    if (wv >= 1) woff += wsum[0];
    if (wv >= 2) woff += wsum[1];
    if (wv >= 3) woff += wsum[2];
    int exc = woff + inc - s;
    #pragma unroll
    for (int i = 0; i < 4; i++) { int idx = base + i; if (idx < n) rowptr[idx] = exc; exc += v[i]; }
    if (t == 255) aux[blk] = woff + inc;
}

__global__ __launch_bounds__(64) void k_scan_b(int* __restrict__ aux, int nblk)
{
    int t = threadIdx.x;
    int v = (t < nblk) ? aux[t] : 0;
    int inc = v;
    #pragma unroll
    for (int off = 1; off < 64; off <<= 1) {
        int u = __shfl_up(inc, off);
        if (t >= off) inc += u;
    }
    if (t < nblk) aux[t] = inc - v;   // exclusive
}

__global__ __launch_bounds__(256) void k_scan_c(
    int* __restrict__ rowptr, int* __restrict__ wofs,
    const int* __restrict__ aux, int n)
{
    int i = blockIdx.x * 256 + threadIdx.x;
    if (i < n) {
        int r = rowptr[i] + aux[i >> 10];
        rowptr[i] = r;
        wofs[i] = r;
    }
}

__global__ __launch_bounds__(256) void k_fill(
    const int* __restrict__ ei, const int* __restrict__ flags,
    int* __restrict__ wofs, int* __restrict__ adj, int E, int nnodes)
{
    int e64 = flags[2];
    int base = (blockIdx.x * 256 + threadIdx.x) * 4;
    #pragma unroll
    for (int j = 0; j < 4; j++) {
        int e = base + j;
        if (e >= E) return;
        int s, d;
        if (e64) { s = ei[2 * e]; d = ei[2 * (E + e)]; }
        else     { s = ei[e];     d = ei[E + e]; }
        if ((unsigned)d >= (unsigned)nnodes) continue;
        if ((unsigned)s >= (unsigned)nnodes) s = 0;
        int slot = atomicAdd(&wofs[d], 1);
        adj[slot] = s;
    }
}

// ---------------------------------------------------------------------------
// Gather-mean (bf16 rows): one wave per dst node, lane owns 2 channels,
// 4-edge unroll with independent accumulators for MLP.
// ---------------------------------------------------------------------------
__global__ __launch_bounds__(256) void k_agg(
    const unsigned short* __restrict__ xB,
    const int* __restrict__ rowptr, const int* __restrict__ deg,
    const int* __restrict__ adj, unsigned short* __restrict__ meanB, int n)
{
    int wid = (blockIdx.x * 256 + threadIdx.x) >> 6;   // node id
    if (wid >= n) return;
    int lane = threadIdx.x & 63;
    int start = rowptr[wid], dc = deg[wid];
    float a0 = 0.f, a1 = 0.f, b0 = 0.f, b1 = 0.f;
    float c0 = 0.f, c1 = 0.f, d0 = 0.f, d1 = 0.f;
    int i = 0;
    for (; i + 3 < dc; i += 4) {
        int s0 = adj[start + i],     s1 = adj[start + i + 1];
        int s2 = adj[start + i + 2], s3 = adj[start + i + 3];
        unsigned int p0 = *(const unsigned int*)&xB[(size_t)s0 * 128 + lane * 2];
        unsigned int p1 = *(const unsigned int*)&xB[(size_t)s1 * 128 + lane * 2];
        unsigned int p2 = *(const unsigned int*)&xB[(size_t)s2 * 128 + lane * 2];
        unsigned int p3 = *(const unsigned int*)&xB[(size_t)s3 * 128 + lane * 2];
        a0 += bf2f((unsigned short)p0); a1 += bf2f((unsigned short)(p0 >> 16));
        b0 += bf2f((unsigned short)p1); b1 += bf2f((unsigned short)(p1 >> 16));
        c0 += bf2f((unsigned short)p2); c1 += bf2f((unsigned short)(p2 >> 16));
        d0 += bf2f((unsigned short)p3); d1 += bf2f((unsigned short)(p3 >> 16));
    }
    for (; i < dc; i++) {
        int s0 = adj[start + i];
        unsigned int p0 = *(const unsigned int*)&xB[(size_t)s0 * 128 + lane * 2];
        a0 += bf2f((unsigned short)p0); a1 += bf2f((unsigned short)(p0 >> 16));
    }
    float inv = 1.f / fmaxf((float)dc, 1.f);
    unsigned int out = (unsigned int)f2bf((a0 + b0 + c0 + d0) * inv) |
                       ((unsigned int)f2bf((a1 + b1 + c1 + d1) * inv) << 16);
    *(unsigned int*)&meanB[(size_t)wid * 128 + lane * 2] = out;
}

// ---------------------------------------------------------------------------
// GEMM1: h = [mean | xbf] (32x256 tile) @ W1p (256x128) + bias1.
// Writes h (fp32 or bf16 per flags[0]) and relu(h) as internal bf16 xemb.
// ---------------------------------------------------------------------------
__global__ __launch_bounds__(256) void k_gemm1(
    const unsigned short* __restrict__ meanB,
    const unsigned short* __restrict__ xbf, const int* __restrict__ flags,
    const unsigned short* __restrict__ Wp,
    const float* __restrict__ bias, void* __restrict__ outh,
    unsigned short* __restrict__ xemb, int nrows)
{
    constexpr int BN = 128, NTW = 2;
    __shared__ __align__(16) unsigned short Alds[32 * 264];
    __shared__ __align__(16) unsigned short Blds[4 * BN * 8];
    int tid = threadIdx.x;
    int row0 = blockIdx.x * 32;
    int xf32 = flags[0];
    {
        int r = tid >> 3, c0 = (tid & 7) * 16;
        int rg = row0 + r; if (rg >= nrows) rg = nrows - 1;
        const u32x4* mp = (const u32x4*)(meanB + (size_t)rg * 128 + c0);
        *(u32x4*)&Alds[r * 264 + c0]     = mp[0];
        *(u32x4*)&Alds[r * 264 + c0 + 8] = mp[1];
        const u32x4* xp = (const u32x4*)(xbf + (size_t)rg * 128 + c0);
        *(u32x4*)&Alds[r * 264 + 128 + c0]     = xp[0];
        *(u32x4*)&Alds[r * 264 + 128 + c0 + 8] = xp[1];
    }
    f32x4 acc[2][NTW];
    #pragma unroll
    for (int a = 0; a < 2; a++)
        #pragma unroll
        for (int b = 0; b < NTW; b++) acc[a][b] = f32x4{0.f, 0.f, 0.f, 0.f};
    int lane = tid & 63, wv = tid >> 6, lh = lane & 15, lq = lane >> 4;
    for (int ks = 0; ks < 8; ++ks) {
        __syncthreads();
        const unsigned short* wsrc = Wp + ks * (4 * BN * 8);
        #pragma unroll
        for (int i = 0; i < (4 * BN) / 256; i++) {
            int ch = i * 256 + tid;
            *(u32x4*)&Blds[ch * 8] = *(const u32x4*)&wsrc[ch * 8];
        }
        __syncthreads();
        bf16x8 a0 = *(const bf16x8*)&Alds[lh * 264 + ks * 32 + lq * 8];
        bf16x8 a1 = *(const bf16x8*)&Alds[(16 + lh) * 264 + ks * 32 + lq * 8];
        #pragma unroll
        for (int i = 0; i < NTW; i++) {
            int col = (wv + 4 * i) * 16 + lh;
            bf16x8 bfr = *(const bf16x8*)&Blds[(lq * BN + col) * 8];
            acc[0][i] = __builtin_amdgcn_mfma_f32_16x16x32_bf16(a0, bfr, acc[0][i], 0, 0, 0);
            acc[1][i] = __builtin_amdgcn_mfma_f32_16x16x32_bf16(a1, bfr, acc[1][i], 0, 0, 0);
        }
    }
    float* outF = (float*)outh;
    unsigned short* outB = (unsigned short*)outh;
    #pragma unroll
    for (int rt = 0; rt < 2; ++rt)
        #pragma unroll
        for (int i = 0; i < NTW; i++)
            #pragma unroll
            for (int j = 0; j < 4; j++) {
                int r = row0 + rt * 16 + lq * 4 + j;
                if (r < nrows) {
                    int c = (wv + 4 * i) * 16 + lh;
                    float v = acc[rt][i][j] + bias[c];
                    if (xf32) outF[(size_t)r * 128 + c] = v;
                    else      outB[(size_t)r * 128 + c] = f2bf(v);
                    xemb[(size_t)r * 128 + c] = f2bf(fmaxf(v, 0.f));
                }
            }
}

// ---------------------------------------------------------------------------
// GEMM2 + fused log_softmax (reads meanB + xemb).
// ---------------------------------------------------------------------------
__global__ __launch_bounds__(256) void k_gemm2(
    const unsigned short* __restrict__ meanB,
    const unsigned short* __restrict__ xf, const unsigned short* __restrict__ Wp,
    const float* __restrict__ bias, const int* __restrict__ flags,
    void* __restrict__ outbase, int nrows)
{
    constexpr int BN = 320, NTW = 5;
    __shared__ __align__(16) char smem[41216];
    unsigned short* Alds = (unsigned short*)smem;
    unsigned short* Blds = (unsigned short*)(smem + 16896);
    float* outT = (float*)smem;
    float* Lbuf = (float*)(smem + 41088);
    int tid = threadIdx.x;
    int row0 = blockIdx.x * 32;
    int xf32 = flags[0];
    {
        int r = tid >> 3, c0 = (tid & 7) * 16;
        int rg = row0 + r; if (rg >= nrows) rg = nrows - 1;
        const u32x4* mp = (const u32x4*)(meanB + (size_t)rg * 128 + c0);
        *(u32x4*)&Alds[r * 264 + c0]     = mp[0];
        *(u32x4*)&Alds[r * 264 + c0 + 8] = mp[1];
        const u32x4* xp = (const u32x4*)(xf + (size_t)rg * 128 + c0);
        *(u32x4*)&Alds[r * 264 + 128 + c0]     = xp[0];
        *(u32x4*)&Alds[r * 264 + 128 + c0 + 8] = xp[1];
    }
    f32x4 acc[2][NTW];
    #pragma unroll
    for (int a = 0; a < 2; a++)
        #pragma unroll
        for (int b = 0; b < NTW; b++) acc[a][b] = f32x4{0.f, 0.f, 0.f, 0.f};
    int lane = tid & 63, wv = tid >> 6, lh = lane & 15, lq = lane >> 4;
    for (int ks = 0; ks < 8; ++ks) {
        __syncthreads();
        const unsigned short* wsrc = Wp + ks * (4 * BN * 8);
        #pragma unroll
        for (int i = 0; i < (4 * BN) / 256; i++) {
            int ch = i * 256 + tid;
            *(u32x4*)&Blds[ch * 8] = *(const u32x4*)&wsrc[ch * 8];
        }
        __syncthreads();
        bf16x8 a0 = *(const bf16x8*)&Alds[lh * 264 + ks * 32 + lq * 8];
        bf16x8 a1 = *(const bf16x8*)&Alds[(16 + lh) * 264 + ks * 32 + lq * 8];
        #pragma unroll
        for (int i = 0; i < NTW; i++) {
            int col = (wv + 4 * i) * 16 + lh;
            bf16x8 bfr = *(const bf16x8*)&Blds[(lq * BN + col) * 8];
            acc[0][i] = __builtin_amdgcn_mfma_f32_16x16x32_bf16(a0, bfr, acc[0][i], 0, 0, 0);
            acc[1][i] = __builtin_amdgcn_mfma_f32_16x16x32_bf16(a1, bfr, acc[1][i], 0, 0, 0);
        }
    }
    __syncthreads();
    #pragma unroll
    for (int rt = 0; rt < 2; ++rt)
        #pragma unroll
        for (int i = 0; i < NTW; i++)
            #pragma unroll
            for (int j = 0; j < 4; j++) {
                int rl = rt * 16 + lq * 4 + j;
                int c  = (wv + 4 * i) * 16 + lh;
                outT[rl * 321 + c] = acc[rt][i][j] + bias[c];
            }
    __syncthreads();
    {
        int r = tid >> 3, g = tid & 7;
        float m = -1e30f;
        for (int c = g; c < 300; c += 8) m = fmaxf(m, outT[r * 321 + c]);
        m = fmaxf(m, __shfl_xor(m, 1, 8));
        m = fmaxf(m, __shfl_xor(m, 2, 8));
        m = fmaxf(m, __shfl_xor(m, 4, 8));
        float s = 0.f;
        for (int c = g; c < 300; c += 8) s += __expf(outT[r * 321 + c] - m);
        s += __shfl_xor(s, 1, 8);
        s += __shfl_xor(s, 2, 8);
        s += __shfl_xor(s, 4, 8);
        if (g == 0) Lbuf[r] = m + __logf(s);
    }
    __syncthreads();
    float* out1F = (float*)outbase + (size_t)nrows * 128;
    unsigned short* out1B = (unsigned short*)outbase + (size_t)nrows * 128;
    for (int i = tid; i < 32 * 300; i += 256) {
        int r = i / 300, c = i - r * 300;
        int rg = row0 + r;
        if (rg < nrows) {
            float v = outT[r * 321 + c] - Lbuf[r];
            if (xf32) out1F[(size_t)rg * 300 + c] = v;
            else      out1B[(size_t)rg * 300 + c] = f2bf(v);
        }
    }
}

// ---------------------------------------------------------------------------
extern "C" void kernel_launch(void* const* d_in, const int* in_sizes, int n_in,
                              void* d_out, int out_size, void* d_ws, size_t ws_size,
                              hipStream_t stream)
{
    const void* x     = d_in[0];
    const int*  ei    = (const int*)d_in[1];
    const void* Wl    = d_in[2];
    const void* bl    = d_in[3];
    const void* Wr    = d_in[4];
    const void* Wsk   = d_in[5];
    const void* bsk   = d_in[6];
    const void* gamma = d_in[7];
    const void* beta  = d_in[8];
    const void* rmean = d_in[9];
    const void* rvar  = d_in[10];
    const void* Wlo   = d_in[11];
    const void* blo   = d_in[12];
    const void* Wro   = d_in[13];

    int N = in_sizes[0] / 128;
    int E = in_sizes[1] / 2;
    long nelem = (long)N * 128;

    char* ws = (char*)d_ws;
    size_t off = 0;
    int* flags = (int*)(ws + off);            off += 256;
    unsigned short* xbf   = (unsigned short*)(ws + off); off += (size_t)N * 128 * 2;
    unsigned short* meanB = (unsigned short*)(ws + off); off += (size_t)N * 128 * 2;
    unsigned short* xemb  = (unsigned short*)(ws + off); off += (size_t)N * 128 * 2;
    off = (off + 255) & ~(size_t)255;
    int* deg    = (int*)(ws + off);           off += (size_t)N * 4;
    int* rowptr = (int*)(ws + off);           off += (size_t)N * 4;
    int* wofs   = (int*)(ws + off);           off += (size_t)N * 4;
    int* aux    = (int*)(ws + off);           off += 256;
    int* adj    = (int*)(ws + off);           off += (size_t)E * 4;
    off = (off + 255) & ~(size_t)255;
    unsigned short* W1p = (unsigned short*)(ws + off);  off += 32768 * 2;
    unsigned short* W2p = (unsigned short*)(ws + off);  off += 81920 * 2;
    float* bias1 = (float*)(ws + off);        off += 512;
    float* bias2 = (float*)(ws + off);        off += 1280;

    int e4grid = (E + 1023) / 1024;           // 4 edges/thread
    int sblk   = (N + 1023) / 1024;
    int cgrid  = (N + 255) / 256;
    int agrid  = (N + 3) / 4;                 // 4 nodes (waves) per block
    int ggrid  = (N + 31) / 32;
    int tgrid  = (int)((nelem / 8 + 255) / 256);

    hipMemsetAsync(deg, 0, (size_t)N * 4, stream);
    k_detect<<<1, 64, 0, stream>>>((const unsigned int*)x, (const unsigned int*)Wl,
                                   (const unsigned int*)ei, flags);
    k_tobf<<<tgrid, 256, 0, stream>>>(x, flags, xbf, nelem);
    k_fold1<<<128, 256, 0, stream>>>(Wl, Wr, Wsk, gamma, rvar, flags, W1p);
    k_fold2<<<320, 256, 0, stream>>>(Wlo, Wro, flags, W2p);
    k_foldb<<<1, 512, 0, stream>>>(bl, bsk, rmean, beta, gamma, rvar, blo, flags, bias1, bias2);

    // CSR build (shared by both layers)
    k_hist<<<e4grid, 256, 0, stream>>>(ei, flags, deg, E, N);
    k_scan_a<<<sblk, 256, 0, stream>>>(deg, rowptr, aux, N);
    k_scan_b<<<1, 64, 0, stream>>>(aux, sblk);
    k_scan_c<<<cgrid, 256, 0, stream>>>(rowptr, wofs, aux, N);
    k_fill<<<e4grid, 256, 0, stream>>>(ei, flags, wofs, adj, E, N);

    // layer 0
    k_agg<<<agrid, 256, 0, stream>>>(xbf, rowptr, deg, adj, meanB, N);
    k_gemm1<<<ggrid, 256, 0, stream>>>(meanB, xbf, flags, W1p, bias1, d_out, xemb, N);

    // layer 1
    k_agg<<<agrid, 256, 0, stream>>>(xemb, rowptr, deg, adj, meanB, N);
    k_gemm2<<<ggrid, 256, 0, stream>>>(meanB, xemb, W2p, bias2, flags, d_out, N);
}

// Round 6
// 220.369 us; speedup vs baseline: 3.7000x; 1.2372x over previous
//
#include <hip/hip_runtime.h>

typedef __attribute__((__ext_vector_type__(8))) __bf16 bf16x8;
typedef __attribute__((__ext_vector_type__(4))) float f32x4;
typedef __attribute__((__ext_vector_type__(4))) unsigned int u32x4;

__device__ __forceinline__ float bf2f(unsigned short u) {
    return __uint_as_float(((unsigned int)u) << 16);
}
__device__ __forceinline__ unsigned short f2bf(float f) {
    unsigned int u = __float_as_uint(f);
    u += 0x7FFFu + ((u >> 16) & 1u);   // RNE
    return (unsigned short)(u >> 16);
}

// ---------------------------------------------------------------------------
// Runtime dtype detector (validated round 3/4). flags[0]=x fp32,
// flags[1]=weights fp32, flags[2]=edges int64.
// ---------------------------------------------------------------------------
__device__ __forceinline__ bool low_short_is_bf16like(unsigned int w) {
    unsigned int lo = w & 0xFFFFu;
    if (lo == 0u || lo == 0x8000u) return true;
    unsigned int e = (lo >> 7) & 0xFFu;
    return (e >= 0x6Cu && e <= 0x8Cu);
}

__global__ __launch_bounds__(64) void k_detect(
    const unsigned int* __restrict__ x, const unsigned int* __restrict__ wl,
    const unsigned int* __restrict__ ei, int* __restrict__ flags)
{
    int t = threadIdx.x;
    int xv = __popcll(__ballot(low_short_is_bf16like(x[t])));
    int wv = __popcll(__ballot(low_short_is_bf16like(wl[t])));
    unsigned int o1 = ei[2 * t + 1];
    unsigned int o2 = ei[2 * t + 129];
    bool oddzero = (o1 == 0u) && (o2 == 0u);
    int e64 = __all(oddzero) ? 1 : 0;
    if (t == 0) {
        flags[0] = (xv < 32) ? 1 : 0;
        flags[1] = (wv < 32) ? 1 : 0;
        flags[2] = e64;
    }
}

// ---------------------------------------------------------------------------
// x -> bf16 copy/convert (one pass; both agg layers + GEMM1 consume bf16).
// ---------------------------------------------------------------------------
__global__ __launch_bounds__(256) void k_tobf(
    const void* __restrict__ xv, const int* __restrict__ flags,
    unsigned short* __restrict__ xbf, long nelem)
{
    int xf32 = flags[0];
    long i = ((long)blockIdx.x * 256 + threadIdx.x) * 8;
    if (i >= nelem) return;
    if (xf32) {
        const float4* p = (const float4*)((const float*)xv + i);
        float4 v0 = p[0], v1 = p[1];
        u32x4 o;
        o.x = (unsigned int)f2bf(v0.x) | ((unsigned int)f2bf(v0.y) << 16);
        o.y = (unsigned int)f2bf(v0.z) | ((unsigned int)f2bf(v0.w) << 16);
        o.z = (unsigned int)f2bf(v1.x) | ((unsigned int)f2bf(v1.y) << 16);
        o.w = (unsigned int)f2bf(v1.z) | ((unsigned int)f2bf(v1.w) << 16);
        *(u32x4*)&xbf[i] = o;
    } else {
        *(u32x4*)&xbf[i] = *(const u32x4*)((const unsigned short*)xv + i);
    }
}

// ---------------------------------------------------------------------------
// Weight folding (unchanged).
// ---------------------------------------------------------------------------
__global__ __launch_bounds__(256) void k_fold1(
    const void* __restrict__ Wl, const void* __restrict__ Wr,
    const void* __restrict__ Wsk, const void* __restrict__ gamma,
    const void* __restrict__ rvar, const int* __restrict__ flags,
    unsigned short* __restrict__ W1p)
{
    int wf32 = flags[1];
    int idx = blockIdx.x * 256 + threadIdx.x;
    int kb = idx >> 10;
    int c  = (idx >> 3) & 127;
    int k7 = idx & 7;
    int k  = kb * 8 + k7;
    float g, rv, w;
    if (wf32) {
        g  = ((const float*)gamma)[c];
        rv = ((const float*)rvar)[c];
        if (k < 128) w = ((const float*)Wl)[k * 128 + c];
        else { int kk = k - 128;
               w = ((const float*)Wr)[kk * 128 + c] + ((const float*)Wsk)[kk * 128 + c]; }
    } else {
        g  = bf2f(((const unsigned short*)gamma)[c]);
        rv = bf2f(((const unsigned short*)rvar)[c]);
        if (k < 128) w = bf2f(((const unsigned short*)Wl)[k * 128 + c]);
        else { int kk = k - 128;
               w = bf2f(((const unsigned short*)Wr)[kk * 128 + c]) +
                   bf2f(((const unsigned short*)Wsk)[kk * 128 + c]); }
    }
    float s = g * rsqrtf(rv + 1e-5f);
    W1p[idx] = f2bf(w * s);
}

__global__ __launch_bounds__(256) void k_fold2(
    const void* __restrict__ Wlo, const void* __restrict__ Wro,
    const int* __restrict__ flags, unsigned short* __restrict__ W2p)
{
    int wf32 = flags[1];
    int idx = blockIdx.x * 256 + threadIdx.x;
    int kb  = idx / 2560;
    int rem = idx - kb * 2560;
    int c   = rem >> 3;
    int k7  = idx & 7;
    int k   = kb * 8 + k7;
    float w = 0.f;
    if (c < 300) {
        if (wf32)
            w = (k < 128) ? ((const float*)Wlo)[k * 300 + c]
                          : ((const float*)Wro)[(k - 128) * 300 + c];
        else
            w = (k < 128) ? bf2f(((const unsigned short*)Wlo)[k * 300 + c])
                          : bf2f(((const unsigned short*)Wro)[(k - 128) * 300 + c]);
    }
    W2p[idx] = f2bf(w);
}

__global__ __launch_bounds__(512) void k_foldb(
    const void* __restrict__ bl, const void* __restrict__ bsk,
    const void* __restrict__ rmean, const void* __restrict__ beta,
    const void* __restrict__ gamma, const void* __restrict__ rvar,
    const void* __restrict__ blo, const int* __restrict__ flags,
    float* __restrict__ bias1, float* __restrict__ bias2)
{
    int wf32 = flags[1];
    int t = threadIdx.x;
    if (t < 128) {
        float g, rv, b1, b2, rm, be;
        if (wf32) {
            g = ((const float*)gamma)[t]; rv = ((const float*)rvar)[t];
            b1 = ((const float*)bl)[t];   b2 = ((const float*)bsk)[t];
            rm = ((const float*)rmean)[t]; be = ((const float*)beta)[t];
        } else {
            g = bf2f(((const unsigned short*)gamma)[t]); rv = bf2f(((const unsigned short*)rvar)[t]);
            b1 = bf2f(((const unsigned short*)bl)[t]);   b2 = bf2f(((const unsigned short*)bsk)[t]);
            rm = bf2f(((const unsigned short*)rmean)[t]); be = bf2f(((const unsigned short*)beta)[t]);
        }
        float s = g * rsqrtf(rv + 1e-5f);
        bias1[t] = (b1 + b2 - rm) * s + be;
    } else if (t < 448) {
        int c = t - 128;
        float b = 0.f;
        if (c < 300)
            b = wf32 ? ((const float*)blo)[c] : bf2f(((const unsigned short*)blo)[c]);
        bias2[c] = b;
    }
}

// ---------------------------------------------------------------------------
// CSR build, single atomic pass:
//   k_rank : rank[e] = atomicAdd(deg[d],1)   (histogram + slot in one)
//   scan   : rowptr = exclusive_scan(deg)
//   k_place: adj[rowptr[d] + rank[e]] = s    (no atomics)
// ---------------------------------------------------------------------------
__global__ __launch_bounds__(256) void k_rank(
    const int* __restrict__ ei, const int* __restrict__ flags,
    int* __restrict__ deg, int* __restrict__ rank, int E, int nnodes)
{
    int e64 = flags[2];
    int e = blockIdx.x * 256 + threadIdx.x;
    if (e >= E) return;
    int d = e64 ? ei[2 * (E + e)] : ei[E + e];
    int r = 0;
    if ((unsigned)d < (unsigned)nnodes) r = atomicAdd(&deg[d], 1);
    rank[e] = r;
}

__global__ __launch_bounds__(256) void k_place(
    const int* __restrict__ ei, const int* __restrict__ flags,
    const int* __restrict__ rowptr, const int* __restrict__ rank,
    int* __restrict__ adj, int E, int nnodes)
{
    int e64 = flags[2];
    int e = blockIdx.x * 256 + threadIdx.x;
    if (e >= E) return;
    int s, d;
    if (e64) { s = ei[2 * e]; d = ei[2 * (E + e)]; }
    else     { s = ei[e];     d = ei[E + e]; }
    if ((unsigned)d >= (unsigned)nnodes) return;
    if ((unsigned)s >= (unsigned)nnodes) s = 0;
    adj[rowptr[d] + rank[e]] = s;
}

__global__ __launch_bounds__(256) void k_scan_a(
    const int* __restrict__ deg, int* __restrict__ rowptr,
    int* __restrict__ aux, int n)
{
    __shared__ int wsum[4];
    int t = threadIdx.x, blk = blockIdx.x;
    int base = blk * 1024 + t * 4;
    int v[4];
    int s = 0;
    #pragma unroll
    for (int i = 0; i < 4; i++) { int idx = base + i; v[i] = (idx < n) ? deg[idx] : 0; s += v[i]; }
    int lane = t & 63, wv = t >> 6;
    int inc = s;
    #pragma unroll
    for (int off = 1; off < 64; off <<= 1) {
        int u = __shfl_up(inc, off);
        if (lane >= off) inc += u;
    }
    if (lane == 63) wsum[wv] = inc;
    __syncthreads();
    int woff = 0;
    if (wv >= 1) woff += wsum[0];
    if (wv >= 2) woff += wsum[1];
    if (wv >= 3) woff += wsum[2];
    int exc = woff + inc - s;
    #pragma unroll
    for (int i = 0; i < 4; i++) { int idx = base + i; if (idx < n) rowptr[idx] = exc; exc += v[i]; }
    if (t == 255) aux[blk] = woff + inc;
}

__global__ __launch_bounds__(64) void k_scan_b(int* __restrict__ aux, int nblk)
{
    int t = threadIdx.x;
    int v = (t < nblk) ? aux[t] : 0;
    int inc = v;
    #pragma unroll
    for (int off = 1; off < 64; off <<= 1) {
        int u = __shfl_up(inc, off);
        if (t >= off) inc += u;
    }
    if (t < nblk) aux[t] = inc - v;   // exclusive
}

__global__ __launch_bounds__(256) void k_scan_c(
    int* __restrict__ rowptr, const int* __restrict__ aux, int n)
{
    int i = blockIdx.x * 256 + threadIdx.x;
    if (i < n) rowptr[i] = rowptr[i] + aux[i >> 10];
}

// ---------------------------------------------------------------------------
// Gather-mean (bf16 rows): one wave per dst node, lane owns 2 channels,
// 4-edge unroll with independent accumulators for MLP.
// ---------------------------------------------------------------------------
__global__ __launch_bounds__(256) void k_agg(
    const unsigned short* __restrict__ xB,
    const int* __restrict__ rowptr, const int* __restrict__ deg,
    const int* __restrict__ adj, unsigned short* __restrict__ meanB, int n)
{
    int wid = (blockIdx.x * 256 + threadIdx.x) >> 6;   // node id
    if (wid >= n) return;
    int lane = threadIdx.x & 63;
    int start = rowptr[wid], dc = deg[wid];
    float a0 = 0.f, a1 = 0.f, b0 = 0.f, b1 = 0.f;
    float c0 = 0.f, c1 = 0.f, d0 = 0.f, d1 = 0.f;
    int i = 0;
    for (; i + 3 < dc; i += 4) {
        int s0 = adj[start + i],     s1 = adj[start + i + 1];
        int s2 = adj[start + i + 2], s3 = adj[start + i + 3];
        unsigned int p0 = *(const unsigned int*)&xB[(size_t)s0 * 128 + lane * 2];
        unsigned int p1 = *(const unsigned int*)&xB[(size_t)s1 * 128 + lane * 2];
        unsigned int p2 = *(const unsigned int*)&xB[(size_t)s2 * 128 + lane * 2];
        unsigned int p3 = *(const unsigned int*)&xB[(size_t)s3 * 128 + lane * 2];
        a0 += bf2f((unsigned short)p0); a1 += bf2f((unsigned short)(p0 >> 16));
        b0 += bf2f((unsigned short)p1); b1 += bf2f((unsigned short)(p1 >> 16));
        c0 += bf2f((unsigned short)p2); c1 += bf2f((unsigned short)(p2 >> 16));
        d0 += bf2f((unsigned short)p3); d1 += bf2f((unsigned short)(p3 >> 16));
    }
    for (; i < dc; i++) {
        int s0 = adj[start + i];
        unsigned int p0 = *(const unsigned int*)&xB[(size_t)s0 * 128 + lane * 2];
        a0 += bf2f((unsigned short)p0); a1 += bf2f((unsigned short)(p0 >> 16));
    }
    float inv = 1.f / fmaxf((float)dc, 1.f);
    unsigned int out = (unsigned int)f2bf((a0 + b0 + c0 + d0) * inv) |
                       ((unsigned int)f2bf((a1 + b1 + c1 + d1) * inv) << 16);
    *(unsigned int*)&meanB[(size_t)wid * 128 + lane * 2] = out;
}

// ---------------------------------------------------------------------------
// GEMM1: h = [mean | xbf] (32x256 tile) @ W1p (256x128) + bias1.
// Writes h (fp32 or bf16 per flags[0]) and relu(h) as internal bf16 xemb.
// ---------------------------------------------------------------------------
__global__ __launch_bounds__(256) void k_gemm1(
    const unsigned short* __restrict__ meanB,
    const unsigned short* __restrict__ xbf, const int* __restrict__ flags,
    const unsigned short* __restrict__ Wp,
    const float* __restrict__ bias, void* __restrict__ outh,
    unsigned short* __restrict__ xemb, int nrows)
{
    constexpr int BN = 128, NTW = 2;
    __shared__ __align__(16) unsigned short Alds[32 * 264];
    __shared__ __align__(16) unsigned short Blds[4 * BN * 8];
    int tid = threadIdx.x;
    int row0 = blockIdx.x * 32;
    int xf32 = flags[0];
    {
        int r = tid >> 3, c0 = (tid & 7) * 16;
        int rg = row0 + r; if (rg >= nrows) rg = nrows - 1;
        const u32x4* mp = (const u32x4*)(meanB + (size_t)rg * 128 + c0);
        *(u32x4*)&Alds[r * 264 + c0]     = mp[0];
        *(u32x4*)&Alds[r * 264 + c0 + 8] = mp[1];
        const u32x4* xp = (const u32x4*)(xbf + (size_t)rg * 128 + c0);
        *(u32x4*)&Alds[r * 264 + 128 + c0]     = xp[0];
        *(u32x4*)&Alds[r * 264 + 128 + c0 + 8] = xp[1];
    }
    f32x4 acc[2][NTW];
    #pragma unroll
    for (int a = 0; a < 2; a++)
        #pragma unroll
        for (int b = 0; b < NTW; b++) acc[a][b] = f32x4{0.f, 0.f, 0.f, 0.f};
    int lane = tid & 63, wv = tid >> 6, lh = lane & 15, lq = lane >> 4;
    for (int ks = 0; ks < 8; ++ks) {
        __syncthreads();
        const unsigned short* wsrc = Wp + ks * (4 * BN * 8);
        #pragma unroll
        for (int i = 0; i < (4 * BN) / 256; i++) {
            int ch = i * 256 + tid;
            *(u32x4*)&Blds[ch * 8] = *(const u32x4*)&wsrc[ch * 8];
        }
        __syncthreads();
        bf16x8 a0 = *(const bf16x8*)&Alds[lh * 264 + ks * 32 + lq * 8];
        bf16x8 a1 = *(const bf16x8*)&Alds[(16 + lh) * 264 + ks * 32 + lq * 8];
        #pragma unroll
        for (int i = 0; i < NTW; i++) {
            int col = (wv + 4 * i) * 16 + lh;
            bf16x8 bfr = *(const bf16x8*)&Blds[(lq * BN + col) * 8];
            acc[0][i] = __builtin_amdgcn_mfma_f32_16x16x32_bf16(a0, bfr, acc[0][i], 0, 0, 0);
            acc[1][i] = __builtin_amdgcn_mfma_f32_16x16x32_bf16(a1, bfr, acc[1][i], 0, 0, 0);
        }
    }
    float* outF = (float*)outh;
    unsigned short* outB = (unsigned short*)outh;
    #pragma unroll
    for (int rt = 0; rt < 2; ++rt)
        #pragma unroll
        for (int i = 0; i < NTW; i++)
            #pragma unroll
            for (int j = 0; j < 4; j++) {
                int r = row0 + rt * 16 + lq * 4 + j;
                if (r < nrows) {
                    int c = (wv + 4 * i) * 16 + lh;
                    float v = acc[rt][i][j] + bias[c];
                    if (xf32) outF[(size_t)r * 128 + c] = v;
                    else      outB[(size_t)r * 128 + c] = f2bf(v);
                    xemb[(size_t)r * 128 + c] = f2bf(fmaxf(v, 0.f));
                }
            }
}

// ---------------------------------------------------------------------------
// GEMM2 + fused log_softmax (reads meanB + xemb).
// ---------------------------------------------------------------------------
__global__ __launch_bounds__(256) void k_gemm2(
    const unsigned short* __restrict__ meanB,
    const unsigned short* __restrict__ xf, const unsigned short* __restrict__ Wp,
    const float* __restrict__ bias, const int* __restrict__ flags,
    void* __restrict__ outbase, int nrows)
{
    constexpr int BN = 320, NTW = 5;
    __shared__ __align__(16) char smem[41216];
    unsigned short* Alds = (unsigned short*)smem;
    unsigned short* Blds = (unsigned short*)(smem + 16896);
    float* outT = (float*)smem;
    float* Lbuf = (float*)(smem + 41088);
    int tid = threadIdx.x;
    int row0 = blockIdx.x * 32;
    int xf32 = flags[0];
    {
        int r = tid >> 3, c0 = (tid & 7) * 16;
        int rg = row0 + r; if (rg >= nrows) rg = nrows - 1;
        const u32x4* mp = (const u32x4*)(meanB + (size_t)rg * 128 + c0);
        *(u32x4*)&Alds[r * 264 + c0]     = mp[0];
        *(u32x4*)&Alds[r * 264 + c0 + 8] = mp[1];
        const u32x4* xp = (const u32x4*)(xf + (size_t)rg * 128 + c0);
        *(u32x4*)&Alds[r * 264 + 128 + c0]     = xp[0];
        *(u32x4*)&Alds[r * 264 + 128 + c0 + 8] = xp[1];
    }
    f32x4 acc[2][NTW];
    #pragma unroll
    for (int a = 0; a < 2; a++)
        #pragma unroll
        for (int b = 0; b < NTW; b++) acc[a][b] = f32x4{0.f, 0.f, 0.f, 0.f};
    int lane = tid & 63, wv = tid >> 6, lh = lane & 15, lq = lane >> 4;
    for (int ks = 0; ks < 8; ++ks) {
        __syncthreads();
        const unsigned short* wsrc = Wp + ks * (4 * BN * 8);
        #pragma unroll
        for (int i = 0; i < (4 * BN) / 256; i++) {
            int ch = i * 256 + tid;
            *(u32x4*)&Blds[ch * 8] = *(const u32x4*)&wsrc[ch * 8];
        }
        __syncthreads();
        bf16x8 a0 = *(const bf16x8*)&Alds[lh * 264 + ks * 32 + lq * 8];
        bf16x8 a1 = *(const bf16x8*)&Alds[(16 + lh) * 264 + ks * 32 + lq * 8];
        #pragma unroll
        for (int i = 0; i < NTW; i++) {
            int col = (wv + 4 * i) * 16 + lh;
            bf16x8 bfr = *(const bf16x8*)&Blds[(lq * BN + col) * 8];
            acc[0][i] = __builtin_amdgcn_mfma_f32_16x16x32_bf16(a0, bfr, acc[0][i], 0, 0, 0);
            acc[1][i] = __builtin_amdgcn_mfma_f32_16x16x32_bf16(a1, bfr, acc[1][i], 0, 0, 0);
        }
    }
    __syncthreads();
    #pragma unroll
    for (int rt = 0; rt < 2; ++rt)
        #pragma unroll
        for (int i = 0; i < NTW; i++)
            #pragma unroll
            for (int j = 0; j < 4; j++) {
                int rl = rt * 16 + lq * 4 + j;
                int c  = (wv + 4 * i) * 16 + lh;
                outT[rl * 321 + c] = acc[rt][i][j] + bias[c];
            }
    __syncthreads();
    {
        int r = tid >> 3, g = tid & 7;
        float m = -1e30f;
        for (int c = g; c < 300; c += 8) m = fmaxf(m, outT[r * 321 + c]);
        m = fmaxf(m, __shfl_xor(m, 1, 8));
        m = fmaxf(m, __shfl_xor(m, 2, 8));
        m = fmaxf(m, __shfl_xor(m, 4, 8));
        float s = 0.f;
        for (int c = g; c < 300; c += 8) s += __expf(outT[r * 321 + c] - m);
        s += __shfl_xor(s, 1, 8);
        s += __shfl_xor(s, 2, 8);
        s += __shfl_xor(s, 4, 8);
        if (g == 0) Lbuf[r] = m + __logf(s);
    }
    __syncthreads();
    float* out1F = (float*)outbase + (size_t)nrows * 128;
    unsigned short* out1B = (unsigned short*)outbase + (size_t)nrows * 128;
    for (int i = tid; i < 32 * 300; i += 256) {
        int r = i / 300, c = i - r * 300;
        int rg = row0 + r;
        if (rg < nrows) {
            float v = outT[r * 321 + c] - Lbuf[r];
            if (xf32) out1F[(size_t)rg * 300 + c] = v;
            else      out1B[(size_t)rg * 300 + c] = f2bf(v);
        }
    }
}

// ---------------------------------------------------------------------------
extern "C" void kernel_launch(void* const* d_in, const int* in_sizes, int n_in,
                              void* d_out, int out_size, void* d_ws, size_t ws_size,
                              hipStream_t stream)
{
    const void* x     = d_in[0];
    const int*  ei    = (const int*)d_in[1];
    const void* Wl    = d_in[2];
    const void* bl    = d_in[3];
    const void* Wr    = d_in[4];
    const void* Wsk   = d_in[5];
    const void* bsk   = d_in[6];
    const void* gamma = d_in[7];
    const void* beta  = d_in[8];
    const void* rmean = d_in[9];
    const void* rvar  = d_in[10];
    const void* Wlo   = d_in[11];
    const void* blo   = d_in[12];
    const void* Wro   = d_in[13];

    int N = in_sizes[0] / 128;
    int E = in_sizes[1] / 2;
    long nelem = (long)N * 128;

    char* ws = (char*)d_ws;
    size_t off = 0;
    int* flags = (int*)(ws + off);            off += 256;
    unsigned short* xbf   = (unsigned short*)(ws + off); off += (size_t)N * 128 * 2;
    unsigned short* meanB = (unsigned short*)(ws + off); off += (size_t)N * 128 * 2;
    unsigned short* xemb  = (unsigned short*)(ws + off); off += (size_t)N * 128 * 2;
    off = (off + 255) & ~(size_t)255;
    int* deg    = (int*)(ws + off);           off += (size_t)N * 4;
    int* rowptr = (int*)(ws + off);           off += (size_t)N * 4;
    int* rank   = (int*)(ws + off);           off += (size_t)E * 4;
    int* aux    = (int*)(ws + off);           off += 256;
    int* adj    = (int*)(ws + off);           off += (size_t)E * 4;
    off = (off + 255) & ~(size_t)255;
    unsigned short* W1p = (unsigned short*)(ws + off);  off += 32768 * 2;
    unsigned short* W2p = (unsigned short*)(ws + off);  off += 81920 * 2;
    float* bias1 = (float*)(ws + off);        off += 512;
    float* bias2 = (float*)(ws + off);        off += 1280;

    int egrid = (E + 255) / 256;              // 1 edge/thread
    int sblk  = (N + 1023) / 1024;
    int cgrid = (N + 255) / 256;
    int agrid = (N + 3) / 4;                  // 4 nodes (waves) per block
    int ggrid = (N + 31) / 32;
    int tgrid = (int)((nelem / 8 + 255) / 256);

    hipMemsetAsync(deg, 0, (size_t)N * 4, stream);
    k_detect<<<1, 64, 0, stream>>>((const unsigned int*)x, (const unsigned int*)Wl,
                                   (const unsigned int*)ei, flags);
    k_tobf<<<tgrid, 256, 0, stream>>>(x, flags, xbf, nelem);
    k_fold1<<<128, 256, 0, stream>>>(Wl, Wr, Wsk, gamma, rvar, flags, W1p);
    k_fold2<<<320, 256, 0, stream>>>(Wlo, Wro, flags, W2p);
    k_foldb<<<1, 512, 0, stream>>>(bl, bsk, rmean, beta, gamma, rvar, blo, flags, bias1, bias2);

    // CSR build: one atomic pass + scan + non-atomic place
    k_rank<<<egrid, 256, 0, stream>>>(ei, flags, deg, rank, E, N);
    k_scan_a<<<sblk, 256, 0, stream>>>(deg, rowptr, aux, N);
    k_scan_b<<<1, 64, 0, stream>>>(aux, sblk);
    k_scan_c<<<cgrid, 256, 0, stream>>>(rowptr, aux, N);
    k_place<<<egrid, 256, 0, stream>>>(ei, flags, rowptr, rank, adj, E, N);

    // layer 0
    k_agg<<<agrid, 256, 0, stream>>>(xbf, rowptr, deg, adj, meanB, N);
    k_gemm1<<<ggrid, 256, 0, stream>>>(meanB, xbf, flags, W1p, bias1, d_out, xemb, N);

    // layer 1
    k_agg<<<agrid, 256, 0, stream>>>(xemb, rowptr, deg, adj, meanB, N);
    k_gemm2<<<ggrid, 256, 0, stream>>>(meanB, xemb, W2p, bias2, flags, d_out, N);
}

// Round 7
// 204.163 us; speedup vs baseline: 3.9936x; 1.0794x over previous
//
#include <hip/hip_runtime.h>

typedef __attribute__((__ext_vector_type__(8))) __bf16 bf16x8;
typedef __attribute__((__ext_vector_type__(4))) float f32x4;
typedef __attribute__((__ext_vector_type__(4))) unsigned int u32x4;

__device__ __forceinline__ float bf2f(unsigned short u) {
    return __uint_as_float(((unsigned int)u) << 16);
}
__device__ __forceinline__ unsigned short f2bf(float f) {
    unsigned int u = __float_as_uint(f);
    u += 0x7FFFu + ((u >> 16) & 1u);   // RNE
    return (unsigned short)(u >> 16);
}

// ---------------------------------------------------------------------------
// Runtime dtype detector (validated round 3+). flags[0]=x fp32,
// flags[1]=weights fp32, flags[2]=edges int64.
// ---------------------------------------------------------------------------
__device__ __forceinline__ bool low_short_is_bf16like(unsigned int w) {
    unsigned int lo = w & 0xFFFFu;
    if (lo == 0u || lo == 0x8000u) return true;
    unsigned int e = (lo >> 7) & 0xFFu;
    return (e >= 0x6Cu && e <= 0x8Cu);
}

__global__ __launch_bounds__(64) void k_detect(
    const unsigned int* __restrict__ x, const unsigned int* __restrict__ wl,
    const unsigned int* __restrict__ ei, int* __restrict__ flags)
{
    int t = threadIdx.x;
    int xv = __popcll(__ballot(low_short_is_bf16like(x[t])));
    int wv = __popcll(__ballot(low_short_is_bf16like(wl[t])));
    unsigned int o1 = ei[2 * t + 1];
    unsigned int o2 = ei[2 * t + 129];
    bool oddzero = (o1 == 0u) && (o2 == 0u);
    int e64 = __all(oddzero) ? 1 : 0;
    if (t == 0) {
        flags[0] = (xv < 32) ? 1 : 0;
        flags[1] = (wv < 32) ? 1 : 0;
        flags[2] = e64;
    }
}

// ---------------------------------------------------------------------------
// x -> bf16 copy/convert.
// ---------------------------------------------------------------------------
__global__ __launch_bounds__(256) void k_tobf(
    const void* __restrict__ xv, const int* __restrict__ flags,
    unsigned short* __restrict__ xbf, long nelem)
{
    int xf32 = flags[0];
    long i = ((long)blockIdx.x * 256 + threadIdx.x) * 8;
    if (i >= nelem) return;
    if (xf32) {
        const float4* p = (const float4*)((const float*)xv + i);
        float4 v0 = p[0], v1 = p[1];
        u32x4 o;
        o.x = (unsigned int)f2bf(v0.x) | ((unsigned int)f2bf(v0.y) << 16);
        o.y = (unsigned int)f2bf(v0.z) | ((unsigned int)f2bf(v0.w) << 16);
        o.z = (unsigned int)f2bf(v1.x) | ((unsigned int)f2bf(v1.y) << 16);
        o.w = (unsigned int)f2bf(v1.z) | ((unsigned int)f2bf(v1.w) << 16);
        *(u32x4*)&xbf[i] = o;
    } else {
        *(u32x4*)&xbf[i] = *(const u32x4*)((const unsigned short*)xv + i);
    }
}

// ---------------------------------------------------------------------------
// Weight folding (unchanged).
// ---------------------------------------------------------------------------
__global__ __launch_bounds__(256) void k_fold1(
    const void* __restrict__ Wl, const void* __restrict__ Wr,
    const void* __restrict__ Wsk, const void* __restrict__ gamma,
    const void* __restrict__ rvar, const int* __restrict__ flags,
    unsigned short* __restrict__ W1p)
{
    int wf32 = flags[1];
    int idx = blockIdx.x * 256 + threadIdx.x;
    int kb = idx >> 10;
    int c  = (idx >> 3) & 127;
    int k7 = idx & 7;
    int k  = kb * 8 + k7;
    float g, rv, w;
    if (wf32) {
        g  = ((const float*)gamma)[c];
        rv = ((const float*)rvar)[c];
        if (k < 128) w = ((const float*)Wl)[k * 128 + c];
        else { int kk = k - 128;
               w = ((const float*)Wr)[kk * 128 + c] + ((const float*)Wsk)[kk * 128 + c]; }
    } else {
        g  = bf2f(((const unsigned short*)gamma)[c]);
        rv = bf2f(((const unsigned short*)rvar)[c]);
        if (k < 128) w = bf2f(((const unsigned short*)Wl)[k * 128 + c]);
        else { int kk = k - 128;
               w = bf2f(((const unsigned short*)Wr)[kk * 128 + c]) +
                   bf2f(((const unsigned short*)Wsk)[kk * 128 + c]); }
    }
    float s = g * rsqrtf(rv + 1e-5f);
    W1p[idx] = f2bf(w * s);
}

__global__ __launch_bounds__(256) void k_fold2(
    const void* __restrict__ Wlo, const void* __restrict__ Wro,
    const int* __restrict__ flags, unsigned short* __restrict__ W2p)
{
    int wf32 = flags[1];
    int idx = blockIdx.x * 256 + threadIdx.x;
    int kb  = idx / 2560;
    int rem = idx - kb * 2560;
    int c   = rem >> 3;
    int k7  = idx & 7;
    int k   = kb * 8 + k7;
    float w = 0.f;
    if (c < 300) {
        if (wf32)
            w = (k < 128) ? ((const float*)Wlo)[k * 300 + c]
                          : ((const float*)Wro)[(k - 128) * 300 + c];
        else
            w = (k < 128) ? bf2f(((const unsigned short*)Wlo)[k * 300 + c])
                          : bf2f(((const unsigned short*)Wro)[(k - 128) * 300 + c]);
    }
    W2p[idx] = f2bf(w);
}

__global__ __launch_bounds__(512) void k_foldb(
    const void* __restrict__ bl, const void* __restrict__ bsk,
    const void* __restrict__ rmean, const void* __restrict__ beta,
    const void* __restrict__ gamma, const void* __restrict__ rvar,
    const void* __restrict__ blo, const int* __restrict__ flags,
    float* __restrict__ bias1, float* __restrict__ bias2)
{
    int wf32 = flags[1];
    int t = threadIdx.x;
    if (t < 128) {
        float g, rv, b1, b2, rm, be;
        if (wf32) {
            g = ((const float*)gamma)[t]; rv = ((const float*)rvar)[t];
            b1 = ((const float*)bl)[t];   b2 = ((const float*)bsk)[t];
            rm = ((const float*)rmean)[t]; be = ((const float*)beta)[t];
        } else {
            g = bf2f(((const unsigned short*)gamma)[t]); rv = bf2f(((const unsigned short*)rvar)[t]);
            b1 = bf2f(((const unsigned short*)bl)[t]);   b2 = bf2f(((const unsigned short*)bsk)[t]);
            rm = bf2f(((const unsigned short*)rmean)[t]); be = bf2f(((const unsigned short*)beta)[t]);
        }
        float s = g * rsqrtf(rv + 1e-5f);
        bias1[t] = (b1 + b2 - rm) * s + be;
    } else if (t < 448) {
        int c = t - 128;
        float b = 0.f;
        if (c < 300)
            b = wf32 ? ((const float*)blo)[c] : bf2f(((const unsigned short*)blo)[c]);
        bias2[c] = b;
    }
}

// ---------------------------------------------------------------------------
// CSR build, single atomic pass (validated round 6).
// ---------------------------------------------------------------------------
__global__ __launch_bounds__(256) void k_rank(
    const int* __restrict__ ei, const int* __restrict__ flags,
    int* __restrict__ deg, int* __restrict__ rank, int E, int nnodes)
{
    int e64 = flags[2];
    int e = blockIdx.x * 256 + threadIdx.x;
    if (e >= E) return;
    int d = e64 ? ei[2 * (E + e)] : ei[E + e];
    int r = 0;
    if ((unsigned)d < (unsigned)nnodes) r = atomicAdd(&deg[d], 1);
    rank[e] = r;
}

__global__ __launch_bounds__(256) void k_place(
    const int* __restrict__ ei, const int* __restrict__ flags,
    const int* __restrict__ rowptr, const int* __restrict__ rank,
    int* __restrict__ adj, int E, int nnodes)
{
    int e64 = flags[2];
    int e = blockIdx.x * 256 + threadIdx.x;
    if (e >= E) return;
    int s, d;
    if (e64) { s = ei[2 * e]; d = ei[2 * (E + e)]; }
    else     { s = ei[e];     d = ei[E + e]; }
    if ((unsigned)d >= (unsigned)nnodes) return;
    if ((unsigned)s >= (unsigned)nnodes) s = 0;
    adj[rowptr[d] + rank[e]] = s;
}

__global__ __launch_bounds__(256) void k_scan_a(
    const int* __restrict__ deg, int* __restrict__ rowptr,
    int* __restrict__ aux, int n)
{
    __shared__ int wsum[4];
    int t = threadIdx.x, blk = blockIdx.x;
    int base = blk * 1024 + t * 4;
    int v[4];
    int s = 0;
    #pragma unroll
    for (int i = 0; i < 4; i++) { int idx = base + i; v[i] = (idx < n) ? deg[idx] : 0; s += v[i]; }
    int lane = t & 63, wv = t >> 6;
    int inc = s;
    #pragma unroll
    for (int off = 1; off < 64; off <<= 1) {
        int u = __shfl_up(inc, off);
        if (lane >= off) inc += u;
    }
    if (lane == 63) wsum[wv] = inc;
    __syncthreads();
    int woff = 0;
    if (wv >= 1) woff += wsum[0];
    if (wv >= 2) woff += wsum[1];
    if (wv >= 3) woff += wsum[2];
    int exc = woff + inc - s;
    #pragma unroll
    for (int i = 0; i < 4; i++) { int idx = base + i; if (idx < n) rowptr[idx] = exc; exc += v[i]; }
    if (t == 255) aux[blk] = woff + inc;
}

__global__ __launch_bounds__(64) void k_scan_b(int* __restrict__ aux, int nblk)
{
    int t = threadIdx.x;
    int v = (t < nblk) ? aux[t] : 0;
    int inc = v;
    #pragma unroll
    for (int off = 1; off < 64; off <<= 1) {
        int u = __shfl_up(inc, off);
        if (t >= off) inc += u;
    }
    if (t < nblk) aux[t] = inc - v;   // exclusive
}

__global__ __launch_bounds__(256) void k_scan_c(
    int* __restrict__ rowptr, const int* __restrict__ aux, int n)
{
    int i = blockIdx.x * 256 + threadIdx.x;
    if (i < n) rowptr[i] = rowptr[i] + aux[i >> 10];
}

// ---------------------------------------------------------------------------
// Gather-mean (bf16 rows): one wave per dst node, lane owns 2 channels,
// 8-edge unroll with independent accumulators (MLP; grid stays full).
// ---------------------------------------------------------------------------
__global__ __launch_bounds__(256) void k_agg(
    const unsigned short* __restrict__ xB,
    const int* __restrict__ rowptr, const int* __restrict__ deg,
    const int* __restrict__ adj, unsigned short* __restrict__ meanB, int n)
{
    int wid = (blockIdx.x * 256 + threadIdx.x) >> 6;   // node id
    if (wid >= n) return;
    int lane = threadIdx.x & 63;
    int start = rowptr[wid], dc = deg[wid];
    float a0 = 0.f, a1 = 0.f, b0 = 0.f, b1 = 0.f;
    float c0 = 0.f, c1 = 0.f, d0 = 0.f, d1 = 0.f;
    float e0 = 0.f, e1 = 0.f, f0 = 0.f, f1 = 0.f;
    float g0 = 0.f, g1 = 0.f, h0 = 0.f, h1 = 0.f;
    int i = 0;
    for (; i + 7 < dc; i += 8) {
        int s0 = adj[start + i],     s1 = adj[start + i + 1];
        int s2 = adj[start + i + 2], s3 = adj[start + i + 3];
        int s4 = adj[start + i + 4], s5 = adj[start + i + 5];
        int s6 = adj[start + i + 6], s7 = adj[start + i + 7];
        unsigned int p0 = *(const unsigned int*)&xB[(size_t)s0 * 128 + lane * 2];
        unsigned int p1 = *(const unsigned int*)&xB[(size_t)s1 * 128 + lane * 2];
        unsigned int p2 = *(const unsigned int*)&xB[(size_t)s2 * 128 + lane * 2];
        unsigned int p3 = *(const unsigned int*)&xB[(size_t)s3 * 128 + lane * 2];
        unsigned int p4 = *(const unsigned int*)&xB[(size_t)s4 * 128 + lane * 2];
        unsigned int p5 = *(const unsigned int*)&xB[(size_t)s5 * 128 + lane * 2];
        unsigned int p6 = *(const unsigned int*)&xB[(size_t)s6 * 128 + lane * 2];
        unsigned int p7 = *(const unsigned int*)&xB[(size_t)s7 * 128 + lane * 2];
        a0 += bf2f((unsigned short)p0); a1 += bf2f((unsigned short)(p0 >> 16));
        b0 += bf2f((unsigned short)p1); b1 += bf2f((unsigned short)(p1 >> 16));
        c0 += bf2f((unsigned short)p2); c1 += bf2f((unsigned short)(p2 >> 16));
        d0 += bf2f((unsigned short)p3); d1 += bf2f((unsigned short)(p3 >> 16));
        e0 += bf2f((unsigned short)p4); e1 += bf2f((unsigned short)(p4 >> 16));
        f0 += bf2f((unsigned short)p5); f1 += bf2f((unsigned short)(p5 >> 16));
        g0 += bf2f((unsigned short)p6); g1 += bf2f((unsigned short)(p6 >> 16));
        h0 += bf2f((unsigned short)p7); h1 += bf2f((unsigned short)(p7 >> 16));
    }
    for (; i < dc; i++) {
        int s0 = adj[start + i];
        unsigned int p0 = *(const unsigned int*)&xB[(size_t)s0 * 128 + lane * 2];
        a0 += bf2f((unsigned short)p0); a1 += bf2f((unsigned short)(p0 >> 16));
    }
    float inv = 1.f / fmaxf((float)dc, 1.f);
    float t0 = (a0 + b0) + (c0 + d0) + (e0 + f0) + (g0 + h0);
    float t1 = (a1 + b1) + (c1 + d1) + (e1 + f1) + (g1 + h1);
    unsigned int out = (unsigned int)f2bf(t0 * inv) |
                       ((unsigned int)f2bf(t1 * inv) << 16);
    *(unsigned int*)&meanB[(size_t)wid * 128 + lane * 2] = out;
}

// ---------------------------------------------------------------------------
// GEMM1: h = [mean | xbf] (32x256 tile) @ W1p (256x128) + bias1.
// B-fragments read directly from global (L2-resident, fragment-contiguous).
// No barriers in the k-loop; LDS = A tile only.
// ---------------------------------------------------------------------------
__global__ __launch_bounds__(256) void k_gemm1(
    const unsigned short* __restrict__ meanB,
    const unsigned short* __restrict__ xbf, const int* __restrict__ flags,
    const unsigned short* __restrict__ Wp,
    const float* __restrict__ bias, void* __restrict__ outh,
    unsigned short* __restrict__ xemb, int nrows)
{
    constexpr int NTW = 2;
    __shared__ __align__(16) unsigned short Alds[32 * 264];
    int tid = threadIdx.x;
    int row0 = blockIdx.x * 32;
    int xf32 = flags[0];
    {
        int r = tid >> 3, c0 = (tid & 7) * 16;
        int rg = row0 + r; if (rg >= nrows) rg = nrows - 1;
        const u32x4* mp = (const u32x4*)(meanB + (size_t)rg * 128 + c0);
        *(u32x4*)&Alds[r * 264 + c0]     = mp[0];
        *(u32x4*)&Alds[r * 264 + c0 + 8] = mp[1];
        const u32x4* xp = (const u32x4*)(xbf + (size_t)rg * 128 + c0);
        *(u32x4*)&Alds[r * 264 + 128 + c0]     = xp[0];
        *(u32x4*)&Alds[r * 264 + 128 + c0 + 8] = xp[1];
    }
    __syncthreads();
    f32x4 acc[2][NTW];
    #pragma unroll
    for (int a = 0; a < 2; a++)
        #pragma unroll
        for (int b = 0; b < NTW; b++) acc[a][b] = f32x4{0.f, 0.f, 0.f, 0.f};
    int lane = tid & 63, wv = tid >> 6, lh = lane & 15, lq = lane >> 4;
    #pragma unroll
    for (int ks = 0; ks < 8; ++ks) {
        bf16x8 a0 = *(const bf16x8*)&Alds[lh * 264 + ks * 32 + lq * 8];
        bf16x8 a1 = *(const bf16x8*)&Alds[(16 + lh) * 264 + ks * 32 + lq * 8];
        #pragma unroll
        for (int i = 0; i < NTW; i++) {
            int col = (wv + 4 * i) * 16 + lh;
            bf16x8 bfr = *(const bf16x8*)&Wp[(ks * 4 + lq) * 1024 + col * 8];
            acc[0][i] = __builtin_amdgcn_mfma_f32_16x16x32_bf16(a0, bfr, acc[0][i], 0, 0, 0);
            acc[1][i] = __builtin_amdgcn_mfma_f32_16x16x32_bf16(a1, bfr, acc[1][i], 0, 0, 0);
        }
    }
    float* outF = (float*)outh;
    unsigned short* outB = (unsigned short*)outh;
    #pragma unroll
    for (int rt = 0; rt < 2; ++rt)
        #pragma unroll
        for (int i = 0; i < NTW; i++)
            #pragma unroll
            for (int j = 0; j < 4; j++) {
                int r = row0 + rt * 16 + lq * 4 + j;
                if (r < nrows) {
                    int c = (wv + 4 * i) * 16 + lh;
                    float v = acc[rt][i][j] + bias[c];
                    if (xf32) outF[(size_t)r * 128 + c] = v;
                    else      outB[(size_t)r * 128 + c] = f2bf(v);
                    xemb[(size_t)r * 128 + c] = f2bf(fmaxf(v, 0.f));
                }
            }
}

// ---------------------------------------------------------------------------
// GEMM2 + fused log_softmax, register-space epilogue.
// B-fragments from global; per-row max/sum via 16-lane shfl + 4x32 LDS combine.
// ---------------------------------------------------------------------------
__global__ __launch_bounds__(256) void k_gemm2(
    const unsigned short* __restrict__ meanB,
    const unsigned short* __restrict__ xf, const unsigned short* __restrict__ Wp,
    const float* __restrict__ bias, const int* __restrict__ flags,
    void* __restrict__ outbase, int nrows)
{
    constexpr int NTW = 5;
    __shared__ __align__(16) unsigned short Alds[32 * 264];
    __shared__ float redM[4][32];
    __shared__ float redS[4][32];
    int tid = threadIdx.x;
    int row0 = blockIdx.x * 32;
    int xf32 = flags[0];
    {
        int r = tid >> 3, c0 = (tid & 7) * 16;
        int rg = row0 + r; if (rg >= nrows) rg = nrows - 1;
        const u32x4* mp = (const u32x4*)(meanB + (size_t)rg * 128 + c0);
        *(u32x4*)&Alds[r * 264 + c0]     = mp[0];
        *(u32x4*)&Alds[r * 264 + c0 + 8] = mp[1];
        const u32x4* xp = (const u32x4*)(xf + (size_t)rg * 128 + c0);
        *(u32x4*)&Alds[r * 264 + 128 + c0]     = xp[0];
        *(u32x4*)&Alds[r * 264 + 128 + c0 + 8] = xp[1];
    }
    __syncthreads();
    f32x4 acc[2][NTW];
    #pragma unroll
    for (int a = 0; a < 2; a++)
        #pragma unroll
        for (int b = 0; b < NTW; b++) acc[a][b] = f32x4{0.f, 0.f, 0.f, 0.f};
    int lane = tid & 63, wv = tid >> 6, lh = lane & 15, lq = lane >> 4;
    #pragma unroll
    for (int ks = 0; ks < 8; ++ks) {
        bf16x8 a0 = *(const bf16x8*)&Alds[lh * 264 + ks * 32 + lq * 8];
        bf16x8 a1 = *(const bf16x8*)&Alds[(16 + lh) * 264 + ks * 32 + lq * 8];
        #pragma unroll
        for (int i = 0; i < NTW; i++) {
            int col = (wv + 4 * i) * 16 + lh;
            bf16x8 bfr = *(const bf16x8*)&Wp[(ks * 4 + lq) * 2560 + col * 8];
            acc[0][i] = __builtin_amdgcn_mfma_f32_16x16x32_bf16(a0, bfr, acc[0][i], 0, 0, 0);
            acc[1][i] = __builtin_amdgcn_mfma_f32_16x16x32_bf16(a1, bfr, acc[1][i], 0, 0, 0);
        }
    }
    // bias into acc
    #pragma unroll
    for (int rt = 0; rt < 2; ++rt)
        #pragma unroll
        for (int i = 0; i < NTW; i++) {
            int col = (wv + 4 * i) * 16 + lh;
            float b = bias[col];
            #pragma unroll
            for (int j = 0; j < 4; j++) acc[rt][i][j] += b;
        }
    // per-row partial max over valid cols (<300), reduce over 16-lane col group
    float M[2][4];
    #pragma unroll
    for (int rt = 0; rt < 2; ++rt)
        #pragma unroll
        for (int j = 0; j < 4; j++) {
            float m = -3.0e38f;
            #pragma unroll
            for (int i = 0; i < NTW; i++) {
                int col = (wv + 4 * i) * 16 + lh;
                if (col < 300) m = fmaxf(m, acc[rt][i][j]);
            }
            m = fmaxf(m, __shfl_xor(m, 1, 16));
            m = fmaxf(m, __shfl_xor(m, 2, 16));
            m = fmaxf(m, __shfl_xor(m, 4, 16));
            m = fmaxf(m, __shfl_xor(m, 8, 16));
            M[rt][j] = m;
        }
    if (lh == 0) {
        #pragma unroll
        for (int rt = 0; rt < 2; ++rt)
            #pragma unroll
            for (int j = 0; j < 4; j++)
                redM[wv][rt * 16 + lq * 4 + j] = M[rt][j];
    }
    __syncthreads();
    #pragma unroll
    for (int rt = 0; rt < 2; ++rt)
        #pragma unroll
        for (int j = 0; j < 4; j++) {
            int rl = rt * 16 + lq * 4 + j;
            M[rt][j] = fmaxf(fmaxf(redM[0][rl], redM[1][rl]),
                             fmaxf(redM[2][rl], redM[3][rl]));
        }
    // per-row partial sums of exp
    float S[2][4];
    #pragma unroll
    for (int rt = 0; rt < 2; ++rt)
        #pragma unroll
        for (int j = 0; j < 4; j++) {
            float s = 0.f;
            #pragma unroll
            for (int i = 0; i < NTW; i++) {
                int col = (wv + 4 * i) * 16 + lh;
                if (col < 300) s += __expf(acc[rt][i][j] - M[rt][j]);
            }
            s += __shfl_xor(s, 1, 16);
            s += __shfl_xor(s, 2, 16);
            s += __shfl_xor(s, 4, 16);
            s += __shfl_xor(s, 8, 16);
            S[rt][j] = s;
        }
    if (lh == 0) {
        #pragma unroll
        for (int rt = 0; rt < 2; ++rt)
            #pragma unroll
            for (int j = 0; j < 4; j++)
                redS[wv][rt * 16 + lq * 4 + j] = S[rt][j];
    }
    __syncthreads();
    float* out1F = (float*)outbase + (size_t)nrows * 128;
    unsigned short* out1B = (unsigned short*)outbase + (size_t)nrows * 128;
    #pragma unroll
    for (int rt = 0; rt < 2; ++rt)
        #pragma unroll
        for (int j = 0; j < 4; j++) {
            int rl = rt * 16 + lq * 4 + j;
            float Sall = (redS[0][rl] + redS[1][rl]) + (redS[2][rl] + redS[3][rl]);
            float L = M[rt][j] + __logf(Sall);
            int rg = row0 + rl;
            if (rg < nrows) {
                #pragma unroll
                for (int i = 0; i < NTW; i++) {
                    int col = (wv + 4 * i) * 16 + lh;
                    if (col < 300) {
                        float v = acc[rt][i][j] - L;
                        if (xf32) out1F[(size_t)rg * 300 + col] = v;
                        else      out1B[(size_t)rg * 300 + col] = f2bf(v);
                    }
                }
            }
        }
}

// ---------------------------------------------------------------------------
extern "C" void kernel_launch(void* const* d_in, const int* in_sizes, int n_in,
                              void* d_out, int out_size, void* d_ws, size_t ws_size,
                              hipStream_t stream)
{
    const void* x     = d_in[0];
    const int*  ei    = (const int*)d_in[1];
    const void* Wl    = d_in[2];
    const void* bl    = d_in[3];
    const void* Wr    = d_in[4];
    const void* Wsk   = d_in[5];
    const void* bsk   = d_in[6];
    const void* gamma = d_in[7];
    const void* beta  = d_in[8];
    const void* rmean = d_in[9];
    const void* rvar  = d_in[10];
    const void* Wlo   = d_in[11];
    const void* blo   = d_in[12];
    const void* Wro   = d_in[13];

    int N = in_sizes[0] / 128;
    int E = in_sizes[1] / 2;
    long nelem = (long)N * 128;

    char* ws = (char*)d_ws;
    size_t off = 0;
    int* flags = (int*)(ws + off);            off += 256;
    unsigned short* xbf   = (unsigned short*)(ws + off); off += (size_t)N * 128 * 2;
    unsigned short* meanB = (unsigned short*)(ws + off); off += (size_t)N * 128 * 2;
    unsigned short* xemb  = (unsigned short*)(ws + off); off += (size_t)N * 128 * 2;
    off = (off + 255) & ~(size_t)255;
    int* deg    = (int*)(ws + off);           off += (size_t)N * 4;
    int* rowptr = (int*)(ws + off);           off += (size_t)N * 4;
    int* rank   = (int*)(ws + off);           off += (size_t)E * 4;
    int* aux    = (int*)(ws + off);           off += 256;
    int* adj    = (int*)(ws + off);           off += (size_t)E * 4;
    off = (off + 255) & ~(size_t)255;
    unsigned short* W1p = (unsigned short*)(ws + off);  off += 32768 * 2;
    unsigned short* W2p = (unsigned short*)(ws + off);  off += 81920 * 2;
    float* bias1 = (float*)(ws + off);        off += 512;
    float* bias2 = (float*)(ws + off);        off += 1280;

    int egrid = (E + 255) / 256;              // 1 edge/thread
    int sblk  = (N + 1023) / 1024;
    int cgrid = (N + 255) / 256;
    int agrid = (N + 3) / 4;                  // 4 nodes (waves) per block
    int ggrid = (N + 31) / 32;
    int tgrid = (int)((nelem / 8 + 255) / 256);

    hipMemsetAsync(deg, 0, (size_t)N * 4, stream);
    k_detect<<<1, 64, 0, stream>>>((const unsigned int*)x, (const unsigned int*)Wl,
                                   (const unsigned int*)ei, flags);
    k_tobf<<<tgrid, 256, 0, stream>>>(x, flags, xbf, nelem);
    k_fold1<<<128, 256, 0, stream>>>(Wl, Wr, Wsk, gamma, rvar, flags, W1p);
    k_fold2<<<320, 256, 0, stream>>>(Wlo, Wro, flags, W2p);
    k_foldb<<<1, 512, 0, stream>>>(bl, bsk, rmean, beta, gamma, rvar, blo, flags, bias1, bias2);

    // CSR build: one atomic pass + scan + non-atomic place
    k_rank<<<egrid, 256, 0, stream>>>(ei, flags, deg, rank, E, N);
    k_scan_a<<<sblk, 256, 0, stream>>>(deg, rowptr, aux, N);
    k_scan_b<<<1, 64, 0, stream>>>(aux, sblk);
    k_scan_c<<<cgrid, 256, 0, stream>>>(rowptr, aux, N);
    k_place<<<egrid, 256, 0, stream>>>(ei, flags, rowptr, rank, adj, E, N);

    // layer 0
    k_agg<<<agrid, 256, 0, stream>>>(xbf, rowptr, deg, adj, meanB, N);
    k_gemm1<<<ggrid, 256, 0, stream>>>(meanB, xbf, flags, W1p, bias1, d_out, xemb, N);

    // layer 1
    k_agg<<<agrid, 256, 0, stream>>>(xemb, rowptr, deg, adj, meanB, N);
    k_gemm2<<<ggrid, 256, 0, stream>>>(meanB, xemb, W2p, bias2, flags, d_out, N);
}

// Round 8
// 191.001 us; speedup vs baseline: 4.2689x; 1.0689x over previous
//
#include <hip/hip_runtime.h>

typedef __attribute__((__ext_vector_type__(8))) __bf16 bf16x8;
typedef __attribute__((__ext_vector_type__(4))) float f32x4;
typedef __attribute__((__ext_vector_type__(4))) unsigned int u32x4;

__device__ __forceinline__ float bf2f(unsigned short u) {
    return __uint_as_float(((unsigned int)u) << 16);
}
__device__ __forceinline__ unsigned short f2bf(float f) {
    unsigned int u = __float_as_uint(f);
    u += 0x7FFFu + ((u >> 16) & 1u);   // RNE
    return (unsigned short)(u >> 16);
}

// ---------------------------------------------------------------------------
// Runtime dtype detector (validated round 3+). flags[0]=x fp32,
// flags[1]=weights fp32, flags[2]=edges int64.
// ---------------------------------------------------------------------------
__device__ __forceinline__ bool low_short_is_bf16like(unsigned int w) {
    unsigned int lo = w & 0xFFFFu;
    if (lo == 0u || lo == 0x8000u) return true;
    unsigned int e = (lo >> 7) & 0xFFu;
    return (e >= 0x6Cu && e <= 0x8Cu);
}

__global__ __launch_bounds__(64) void k_detect(
    const unsigned int* __restrict__ x, const unsigned int* __restrict__ wl,
    const unsigned int* __restrict__ ei, int* __restrict__ flags)
{
    int t = threadIdx.x;
    int xv = __popcll(__ballot(low_short_is_bf16like(x[t])));
    int wv = __popcll(__ballot(low_short_is_bf16like(wl[t])));
    unsigned int o1 = ei[2 * t + 1];
    unsigned int o2 = ei[2 * t + 129];
    bool oddzero = (o1 == 0u) && (o2 == 0u);
    int e64 = __all(oddzero) ? 1 : 0;
    if (t == 0) {
        flags[0] = (xv < 32) ? 1 : 0;
        flags[1] = (wv < 32) ? 1 : 0;
        flags[2] = e64;
    }
}

// ---------------------------------------------------------------------------
// x -> bf16 copy/convert.
// ---------------------------------------------------------------------------
__global__ __launch_bounds__(256) void k_tobf(
    const void* __restrict__ xv, const int* __restrict__ flags,
    unsigned short* __restrict__ xbf, long nelem)
{
    int xf32 = flags[0];
    long i = ((long)blockIdx.x * 256 + threadIdx.x) * 8;
    if (i >= nelem) return;
    if (xf32) {
        const float4* p = (const float4*)((const float*)xv + i);
        float4 v0 = p[0], v1 = p[1];
        u32x4 o;
        o.x = (unsigned int)f2bf(v0.x) | ((unsigned int)f2bf(v0.y) << 16);
        o.y = (unsigned int)f2bf(v0.z) | ((unsigned int)f2bf(v0.w) << 16);
        o.z = (unsigned int)f2bf(v1.x) | ((unsigned int)f2bf(v1.y) << 16);
        o.w = (unsigned int)f2bf(v1.z) | ((unsigned int)f2bf(v1.w) << 16);
        *(u32x4*)&xbf[i] = o;
    } else {
        *(u32x4*)&xbf[i] = *(const u32x4*)((const unsigned short*)xv + i);
    }
}

// ---------------------------------------------------------------------------
// Weight folding (unchanged).
// ---------------------------------------------------------------------------
__global__ __launch_bounds__(256) void k_fold1(
    const void* __restrict__ Wl, const void* __restrict__ Wr,
    const void* __restrict__ Wsk, const void* __restrict__ gamma,
    const void* __restrict__ rvar, const int* __restrict__ flags,
    unsigned short* __restrict__ W1p)
{
    int wf32 = flags[1];
    int idx = blockIdx.x * 256 + threadIdx.x;
    int kb = idx >> 10;
    int c  = (idx >> 3) & 127;
    int k7 = idx & 7;
    int k  = kb * 8 + k7;
    float g, rv, w;
    if (wf32) {
        g  = ((const float*)gamma)[c];
        rv = ((const float*)rvar)[c];
        if (k < 128) w = ((const float*)Wl)[k * 128 + c];
        else { int kk = k - 128;
               w = ((const float*)Wr)[kk * 128 + c] + ((const float*)Wsk)[kk * 128 + c]; }
    } else {
        g  = bf2f(((const unsigned short*)gamma)[c]);
        rv = bf2f(((const unsigned short*)rvar)[c]);
        if (k < 128) w = bf2f(((const unsigned short*)Wl)[k * 128 + c]);
        else { int kk = k - 128;
               w = bf2f(((const unsigned short*)Wr)[kk * 128 + c]) +
                   bf2f(((const unsigned short*)Wsk)[kk * 128 + c]); }
    }
    float s = g * rsqrtf(rv + 1e-5f);
    W1p[idx] = f2bf(w * s);
}

__global__ __launch_bounds__(256) void k_fold2(
    const void* __restrict__ Wlo, const void* __restrict__ Wro,
    const int* __restrict__ flags, unsigned short* __restrict__ W2p)
{
    int wf32 = flags[1];
    int idx = blockIdx.x * 256 + threadIdx.x;
    int kb  = idx / 2560;
    int rem = idx - kb * 2560;
    int c   = rem >> 3;
    int k7  = idx & 7;
    int k   = kb * 8 + k7;
    float w = 0.f;
    if (c < 300) {
        if (wf32)
            w = (k < 128) ? ((const float*)Wlo)[k * 300 + c]
                          : ((const float*)Wro)[(k - 128) * 300 + c];
        else
            w = (k < 128) ? bf2f(((const unsigned short*)Wlo)[k * 300 + c])
                          : bf2f(((const unsigned short*)Wro)[(k - 128) * 300 + c]);
    }
    W2p[idx] = f2bf(w);
}

__global__ __launch_bounds__(512) void k_foldb(
    const void* __restrict__ bl, const void* __restrict__ bsk,
    const void* __restrict__ rmean, const void* __restrict__ beta,
    const void* __restrict__ gamma, const void* __restrict__ rvar,
    const void* __restrict__ blo, const int* __restrict__ flags,
    float* __restrict__ bias1, float* __restrict__ bias2)
{
    int wf32 = flags[1];
    int t = threadIdx.x;
    if (t < 128) {
        float g, rv, b1, b2, rm, be;
        if (wf32) {
            g = ((const float*)gamma)[t]; rv = ((const float*)rvar)[t];
            b1 = ((const float*)bl)[t];   b2 = ((const float*)bsk)[t];
            rm = ((const float*)rmean)[t]; be = ((const float*)beta)[t];
        } else {
            g = bf2f(((const unsigned short*)gamma)[t]); rv = bf2f(((const unsigned short*)rvar)[t]);
            b1 = bf2f(((const unsigned short*)bl)[t]);   b2 = bf2f(((const unsigned short*)bsk)[t]);
            rm = bf2f(((const unsigned short*)rmean)[t]); be = bf2f(((const unsigned short*)beta)[t]);
        }
        float s = g * rsqrtf(rv + 1e-5f);
        bias1[t] = (b1 + b2 - rm) * s + be;
    } else if (t < 448) {
        int c = t - 128;
        float b = 0.f;
        if (c < 300)
            b = wf32 ? ((const float*)blo)[c] : bf2f(((const unsigned short*)blo)[c]);
        bias2[c] = b;
    }
}

// ---------------------------------------------------------------------------
// CSR build, single atomic pass; rowptr kept block-local, aux holds the
// exclusive block offsets (scan_c folded into consumers).
// ---------------------------------------------------------------------------
__global__ __launch_bounds__(256) void k_rank(
    const int* __restrict__ ei, const int* __restrict__ flags,
    int* __restrict__ deg, int* __restrict__ rank, int E, int nnodes)
{
    int e64 = flags[2];
    int e = blockIdx.x * 256 + threadIdx.x;
    if (e >= E) return;
    int d = e64 ? ei[2 * (E + e)] : ei[E + e];
    int r = 0;
    if ((unsigned)d < (unsigned)nnodes) r = atomicAdd(&deg[d], 1);
    rank[e] = r;
}

template <typename IT>
__global__ __launch_bounds__(256) void k_place(
    const int* __restrict__ ei, const int* __restrict__ flags,
    const int* __restrict__ rowptr, const int* __restrict__ aux,
    const int* __restrict__ rank,
    IT* __restrict__ adj, int E, int nnodes)
{
    int e64 = flags[2];
    int e = blockIdx.x * 256 + threadIdx.x;
    if (e >= E) return;
    int s, d;
    if (e64) { s = ei[2 * e]; d = ei[2 * (E + e)]; }
    else     { s = ei[e];     d = ei[E + e]; }
    if ((unsigned)d >= (unsigned)nnodes) return;
    if ((unsigned)s >= (unsigned)nnodes) s = 0;
    adj[rowptr[d] + aux[d >> 10] + rank[e]] = (IT)s;
}

__global__ __launch_bounds__(256) void k_scan_a(
    const int* __restrict__ deg, int* __restrict__ rowptr,
    int* __restrict__ aux, int n)
{
    __shared__ int wsum[4];
    int t = threadIdx.x, blk = blockIdx.x;
    int base = blk * 1024 + t * 4;
    int v[4];
    int s = 0;
    #pragma unroll
    for (int i = 0; i < 4; i++) { int idx = base + i; v[i] = (idx < n) ? deg[idx] : 0; s += v[i]; }
    int lane = t & 63, wv = t >> 6;
    int inc = s;
    #pragma unroll
    for (int off = 1; off < 64; off <<= 1) {
        int u = __shfl_up(inc, off);
        if (lane >= off) inc += u;
    }
    if (lane == 63) wsum[wv] = inc;
    __syncthreads();
    int woff = 0;
    if (wv >= 1) woff += wsum[0];
    if (wv >= 2) woff += wsum[1];
    if (wv >= 3) woff += wsum[2];
    int exc = woff + inc - s;
    #pragma unroll
    for (int i = 0; i < 4; i++) { int idx = base + i; if (idx < n) rowptr[idx] = exc; exc += v[i]; }
    if (t == 255) aux[blk] = woff + inc;
}

__global__ __launch_bounds__(64) void k_scan_b(int* __restrict__ aux, int nblk)
{
    int t = threadIdx.x;
    int carry = 0;
    for (int base = 0; base < nblk; base += 64) {
        int idx = base + t;
        int v = (idx < nblk) ? aux[idx] : 0;
        int inc = v;
        #pragma unroll
        for (int off = 1; off < 64; off <<= 1) {
            int u = __shfl_up(inc, off);
            if (t >= off) inc += u;
        }
        if (idx < nblk) aux[idx] = carry + inc - v;   // exclusive
        carry += __shfl(inc, 63);
    }
}

// ---------------------------------------------------------------------------
// Gather-mean: one wave per dst node. Half-wave layout: 32 sublanes own 4
// channels each (uint2 = 8B loads); half-waves process alternating edges of
// the SAME node (no inter-node divergence). 4-deep unroll per half = 8 edges
// in flight per wave. Cross-half combine via shfl_xor(32).
// ---------------------------------------------------------------------------
template <typename IT>
__global__ __launch_bounds__(256) void k_agg(
    const unsigned short* __restrict__ xB,
    const int* __restrict__ rowptr, const int* __restrict__ aux,
    const int* __restrict__ deg,
    const IT* __restrict__ adj, unsigned short* __restrict__ meanB, int n)
{
    int wid = (blockIdx.x * 256 + threadIdx.x) >> 6;   // node id
    if (wid >= n) return;
    int lane = threadIdx.x & 63;
    int h  = lane >> 5;          // half-wave: processes edges i+h, i+2+h, ...
    int sl = lane & 31;          // sublane: channels sl*4 .. sl*4+3
    int start = rowptr[wid] + aux[wid >> 10];
    int dc = deg[wid];
    float acc[4][4];
    #pragma unroll
    for (int u = 0; u < 4; u++)
        #pragma unroll
        for (int c = 0; c < 4; c++) acc[u][c] = 0.f;
    int i = 0;
    for (; i + 7 < dc; i += 8) {
        int e0 = (int)adj[start + i + h];
        int e1 = (int)adj[start + i + 2 + h];
        int e2 = (int)adj[start + i + 4 + h];
        int e3 = (int)adj[start + i + 6 + h];
        uint2 p0 = *(const uint2*)&xB[(size_t)e0 * 128 + sl * 4];
        uint2 p1 = *(const uint2*)&xB[(size_t)e1 * 128 + sl * 4];
        uint2 p2 = *(const uint2*)&xB[(size_t)e2 * 128 + sl * 4];
        uint2 p3 = *(const uint2*)&xB[(size_t)e3 * 128 + sl * 4];
        acc[0][0] += bf2f((unsigned short)p0.x); acc[0][1] += bf2f((unsigned short)(p0.x >> 16));
        acc[0][2] += bf2f((unsigned short)p0.y); acc[0][3] += bf2f((unsigned short)(p0.y >> 16));
        acc[1][0] += bf2f((unsigned short)p1.x); acc[1][1] += bf2f((unsigned short)(p1.x >> 16));
        acc[1][2] += bf2f((unsigned short)p1.y); acc[1][3] += bf2f((unsigned short)(p1.y >> 16));
        acc[2][0] += bf2f((unsigned short)p2.x); acc[2][1] += bf2f((unsigned short)(p2.x >> 16));
        acc[2][2] += bf2f((unsigned short)p2.y); acc[2][3] += bf2f((unsigned short)(p2.y >> 16));
        acc[3][0] += bf2f((unsigned short)p3.x); acc[3][1] += bf2f((unsigned short)(p3.x >> 16));
        acc[3][2] += bf2f((unsigned short)p3.y); acc[3][3] += bf2f((unsigned short)(p3.y >> 16));
    }
    for (; i + h < dc; i += 2) {
        int e0 = (int)adj[start + i + h];
        uint2 p0 = *(const uint2*)&xB[(size_t)e0 * 128 + sl * 4];
        acc[0][0] += bf2f((unsigned short)p0.x); acc[0][1] += bf2f((unsigned short)(p0.x >> 16));
        acc[0][2] += bf2f((unsigned short)p0.y); acc[0][3] += bf2f((unsigned short)(p0.y >> 16));
    }
    float t0 = (acc[0][0] + acc[1][0]) + (acc[2][0] + acc[3][0]);
    float t1 = (acc[0][1] + acc[1][1]) + (acc[2][1] + acc[3][1]);
    float t2 = (acc[0][2] + acc[1][2]) + (acc[2][2] + acc[3][2]);
    float t3 = (acc[0][3] + acc[1][3]) + (acc[2][3] + acc[3][3]);
    t0 += __shfl_xor(t0, 32);
    t1 += __shfl_xor(t1, 32);
    t2 += __shfl_xor(t2, 32);
    t3 += __shfl_xor(t3, 32);
    if (h == 0) {
        float inv = 1.f / fmaxf((float)dc, 1.f);
        uint2 o;
        o.x = (unsigned int)f2bf(t0 * inv) | ((unsigned int)f2bf(t1 * inv) << 16);
        o.y = (unsigned int)f2bf(t2 * inv) | ((unsigned int)f2bf(t3 * inv) << 16);
        *(uint2*)&meanB[(size_t)wid * 128 + sl * 4] = o;
    }
}

// ---------------------------------------------------------------------------
// GEMM1: h = [mean | xbf] (32x256 tile) @ W1p (256x128) + bias1.
// B-fragments direct from global (L2-resident); barrier-free k-loop.
// ---------------------------------------------------------------------------
__global__ __launch_bounds__(256) void k_gemm1(
    const unsigned short* __restrict__ meanB,
    const unsigned short* __restrict__ xbf, const int* __restrict__ flags,
    const unsigned short* __restrict__ Wp,
    const float* __restrict__ bias, void* __restrict__ outh,
    unsigned short* __restrict__ xemb, int nrows)
{
    constexpr int NTW = 2;
    __shared__ __align__(16) unsigned short Alds[32 * 264];
    int tid = threadIdx.x;
    int row0 = blockIdx.x * 32;
    int xf32 = flags[0];
    {
        int r = tid >> 3, c0 = (tid & 7) * 16;
        int rg = row0 + r; if (rg >= nrows) rg = nrows - 1;
        const u32x4* mp = (const u32x4*)(meanB + (size_t)rg * 128 + c0);
        *(u32x4*)&Alds[r * 264 + c0]     = mp[0];
        *(u32x4*)&Alds[r * 264 + c0 + 8] = mp[1];
        const u32x4* xp = (const u32x4*)(xbf + (size_t)rg * 128 + c0);
        *(u32x4*)&Alds[r * 264 + 128 + c0]     = xp[0];
        *(u32x4*)&Alds[r * 264 + 128 + c0 + 8] = xp[1];
    }
    __syncthreads();
    f32x4 acc[2][NTW];
    #pragma unroll
    for (int a = 0; a < 2; a++)
        #pragma unroll
        for (int b = 0; b < NTW; b++) acc[a][b] = f32x4{0.f, 0.f, 0.f, 0.f};
    int lane = tid & 63, wv = tid >> 6, lh = lane & 15, lq = lane >> 4;
    #pragma unroll
    for (int ks = 0; ks < 8; ++ks) {
        bf16x8 a0 = *(const bf16x8*)&Alds[lh * 264 + ks * 32 + lq * 8];
        bf16x8 a1 = *(const bf16x8*)&Alds[(16 + lh) * 264 + ks * 32 + lq * 8];
        #pragma unroll
        for (int i = 0; i < NTW; i++) {
            int col = (wv + 4 * i) * 16 + lh;
            bf16x8 bfr = *(const bf16x8*)&Wp[(ks * 4 + lq) * 1024 + col * 8];
            acc[0][i] = __builtin_amdgcn_mfma_f32_16x16x32_bf16(a0, bfr, acc[0][i], 0, 0, 0);
            acc[1][i] = __builtin_amdgcn_mfma_f32_16x16x32_bf16(a1, bfr, acc[1][i], 0, 0, 0);
        }
    }
    float* outF = (float*)outh;
    unsigned short* outB = (unsigned short*)outh;
    #pragma unroll
    for (int rt = 0; rt < 2; ++rt)
        #pragma unroll
        for (int i = 0; i < NTW; i++)
            #pragma unroll
            for (int j = 0; j < 4; j++) {
                int r = row0 + rt * 16 + lq * 4 + j;
                if (r < nrows) {
                    int c = (wv + 4 * i) * 16 + lh;
                    float v = acc[rt][i][j] + bias[c];
                    if (xf32) outF[(size_t)r * 128 + c] = v;
                    else      outB[(size_t)r * 128 + c] = f2bf(v);
                    xemb[(size_t)r * 128 + c] = f2bf(fmaxf(v, 0.f));
                }
            }
}

// ---------------------------------------------------------------------------
// GEMM2 + fused log_softmax, register-space epilogue (validated round 7).
// ---------------------------------------------------------------------------
__global__ __launch_bounds__(256) void k_gemm2(
    const unsigned short* __restrict__ meanB,
    const unsigned short* __restrict__ xf, const unsigned short* __restrict__ Wp,
    const float* __restrict__ bias, const int* __restrict__ flags,
    void* __restrict__ outbase, int nrows)
{
    constexpr int NTW = 5;
    __shared__ __align__(16) unsigned short Alds[32 * 264];
    __shared__ float redM[4][32];
    __shared__ float redS[4][32];
    int tid = threadIdx.x;
    int row0 = blockIdx.x * 32;
    int xf32 = flags[0];
    {
        int r = tid >> 3, c0 = (tid & 7) * 16;
        int rg = row0 + r; if (rg >= nrows) rg = nrows - 1;
        const u32x4* mp = (const u32x4*)(meanB + (size_t)rg * 128 + c0);
        *(u32x4*)&Alds[r * 264 + c0]     = mp[0];
        *(u32x4*)&Alds[r * 264 + c0 + 8] = mp[1];
        const u32x4* xp = (const u32x4*)(xf + (size_t)rg * 128 + c0);
        *(u32x4*)&Alds[r * 264 + 128 + c0]     = xp[0];
        *(u32x4*)&Alds[r * 264 + 128 + c0 + 8] = xp[1];
    }
    __syncthreads();
    f32x4 acc[2][NTW];
    #pragma unroll
    for (int a = 0; a < 2; a++)
        #pragma unroll
        for (int b = 0; b < NTW; b++) acc[a][b] = f32x4{0.f, 0.f, 0.f, 0.f};
    int lane = tid & 63, wv = tid >> 6, lh = lane & 15, lq = lane >> 4;
    #pragma unroll
    for (int ks = 0; ks < 8; ++ks) {
        bf16x8 a0 = *(const bf16x8*)&Alds[lh * 264 + ks * 32 + lq * 8];
        bf16x8 a1 = *(const bf16x8*)&Alds[(16 + lh) * 264 + ks * 32 + lq * 8];
        #pragma unroll
        for (int i = 0; i < NTW; i++) {
            int col = (wv + 4 * i) * 16 + lh;
            bf16x8 bfr = *(const bf16x8*)&Wp[(ks * 4 + lq) * 2560 + col * 8];
            acc[0][i] = __builtin_amdgcn_mfma_f32_16x16x32_bf16(a0, bfr, acc[0][i], 0, 0, 0);
            acc[1][i] = __builtin_amdgcn_mfma_f32_16x16x32_bf16(a1, bfr, acc[1][i], 0, 0, 0);
        }
    }
    #pragma unroll
    for (int rt = 0; rt < 2; ++rt)
        #pragma unroll
        for (int i = 0; i < NTW; i++) {
            int col = (wv + 4 * i) * 16 + lh;
            float b = bias[col];
            #pragma unroll
            for (int j = 0; j < 4; j++) acc[rt][i][j] += b;
        }
    float M[2][4];
    #pragma unroll
    for (int rt = 0; rt < 2; ++rt)
        #pragma unroll
        for (int j = 0; j < 4; j++) {
            float m = -3.0e38f;
            #pragma unroll
            for (int i = 0; i < NTW; i++) {
                int col = (wv + 4 * i) * 16 + lh;
                if (col < 300) m = fmaxf(m, acc[rt][i][j]);
            }
            m = fmaxf(m, __shfl_xor(m, 1, 16));
            m = fmaxf(m, __shfl_xor(m, 2, 16));
            m = fmaxf(m, __shfl_xor(m, 4, 16));
            m = fmaxf(m, __shfl_xor(m, 8, 16));
            M[rt][j] = m;
        }
    if (lh == 0) {
        #pragma unroll
        for (int rt = 0; rt < 2; ++rt)
            #pragma unroll
            for (int j = 0; j < 4; j++)
                redM[wv][rt * 16 + lq * 4 + j] = M[rt][j];
    }
    __syncthreads();
    #pragma unroll
    for (int rt = 0; rt < 2; ++rt)
        #pragma unroll
        for (int j = 0; j < 4; j++) {
            int rl = rt * 16 + lq * 4 + j;
            M[rt][j] = fmaxf(fmaxf(redM[0][rl], redM[1][rl]),
                             fmaxf(redM[2][rl], redM[3][rl]));
        }
    float S[2][4];
    #pragma unroll
    for (int rt = 0; rt < 2; ++rt)
        #pragma unroll
        for (int j = 0; j < 4; j++) {
            float s = 0.f;
            #pragma unroll
            for (int i = 0; i < NTW; i++) {
                int col = (wv + 4 * i) * 16 + lh;
                if (col < 300) s += __expf(acc[rt][i][j] - M[rt][j]);
            }
            s += __shfl_xor(s, 1, 16);
            s += __shfl_xor(s, 2, 16);
            s += __shfl_xor(s, 4, 16);
            s += __shfl_xor(s, 8, 16);
            S[rt][j] = s;
        }
    if (lh == 0) {
        #pragma unroll
        for (int rt = 0; rt < 2; ++rt)
            #pragma unroll
            for (int j = 0; j < 4; j++)
                redS[wv][rt * 16 + lq * 4 + j] = S[rt][j];
    }
    __syncthreads();
    float* out1F = (float*)outbase + (size_t)nrows * 128;
    unsigned short* out1B = (unsigned short*)outbase + (size_t)nrows * 128;
    #pragma unroll
    for (int rt = 0; rt < 2; ++rt)
        #pragma unroll
        for (int j = 0; j < 4; j++) {
            int rl = rt * 16 + lq * 4 + j;
            float Sall = (redS[0][rl] + redS[1][rl]) + (redS[2][rl] + redS[3][rl]);
            float L = M[rt][j] + __logf(Sall);
            int rg = row0 + rl;
            if (rg < nrows) {
                #pragma unroll
                for (int i = 0; i < NTW; i++) {
                    int col = (wv + 4 * i) * 16 + lh;
                    if (col < 300) {
                        float v = acc[rt][i][j] - L;
                        if (xf32) out1F[(size_t)rg * 300 + col] = v;
                        else      out1B[(size_t)rg * 300 + col] = f2bf(v);
                    }
                }
            }
        }
}

// ---------------------------------------------------------------------------
extern "C" void kernel_launch(void* const* d_in, const int* in_sizes, int n_in,
                              void* d_out, int out_size, void* d_ws, size_t ws_size,
                              hipStream_t stream)
{
    const void* x     = d_in[0];
    const int*  ei    = (const int*)d_in[1];
    const void* Wl    = d_in[2];
    const void* bl    = d_in[3];
    const void* Wr    = d_in[4];
    const void* Wsk   = d_in[5];
    const void* bsk   = d_in[6];
    const void* gamma = d_in[7];
    const void* beta  = d_in[8];
    const void* rmean = d_in[9];
    const void* rvar  = d_in[10];
    const void* Wlo   = d_in[11];
    const void* blo   = d_in[12];
    const void* Wro   = d_in[13];

    int N = in_sizes[0] / 128;
    int E = in_sizes[1] / 2;
    long nelem = (long)N * 128;
    bool idx16 = (N <= 65535);

    char* ws = (char*)d_ws;
    size_t off = 0;
    int* flags = (int*)(ws + off);            off += 256;
    unsigned short* xbf   = (unsigned short*)(ws + off); off += (size_t)N * 128 * 2;
    unsigned short* meanB = (unsigned short*)(ws + off); off += (size_t)N * 128 * 2;
    unsigned short* xemb  = (unsigned short*)(ws + off); off += (size_t)N * 128 * 2;
    off = (off + 255) & ~(size_t)255;
    int* deg    = (int*)(ws + off);           off += (size_t)N * 4;
    int* rowptr = (int*)(ws + off);           off += (size_t)N * 4;
    int* rank   = (int*)(ws + off);           off += (size_t)E * 4;
    int* aux    = (int*)(ws + off);           off += 256;
    void* adjv  = (void*)(ws + off);          off += (size_t)E * 4;   // u16 uses half
    off = (off + 255) & ~(size_t)255;
    unsigned short* W1p = (unsigned short*)(ws + off);  off += 32768 * 2;
    unsigned short* W2p = (unsigned short*)(ws + off);  off += 81920 * 2;
    float* bias1 = (float*)(ws + off);        off += 512;
    float* bias2 = (float*)(ws + off);        off += 1280;

    int egrid = (E + 255) / 256;              // 1 edge/thread
    int sblk  = (N + 1023) / 1024;
    int agrid = (N + 3) / 4;                  // 4 node-waves per block
    int ggrid = (N + 31) / 32;
    int tgrid = (int)((nelem / 8 + 255) / 256);

    hipMemsetAsync(deg, 0, (size_t)N * 4, stream);
    k_detect<<<1, 64, 0, stream>>>((const unsigned int*)x, (const unsigned int*)Wl,
                                   (const unsigned int*)ei, flags);
    k_tobf<<<tgrid, 256, 0, stream>>>(x, flags, xbf, nelem);
    k_fold1<<<128, 256, 0, stream>>>(Wl, Wr, Wsk, gamma, rvar, flags, W1p);
    k_fold2<<<320, 256, 0, stream>>>(Wlo, Wro, flags, W2p);
    k_foldb<<<1, 512, 0, stream>>>(bl, bsk, rmean, beta, gamma, rvar, blo, flags, bias1, bias2);

    // CSR build: one atomic pass + scan (block-local + aux); scan_c folded out
    k_rank<<<egrid, 256, 0, stream>>>(ei, flags, deg, rank, E, N);
    k_scan_a<<<sblk, 256, 0, stream>>>(deg, rowptr, aux, N);
    k_scan_b<<<1, 64, 0, stream>>>(aux, sblk);

    if (idx16) {
        unsigned short* adj = (unsigned short*)adjv;
        k_place<unsigned short><<<egrid, 256, 0, stream>>>(ei, flags, rowptr, aux, rank, adj, E, N);
        k_agg<unsigned short><<<agrid, 256, 0, stream>>>(xbf, rowptr, aux, deg, adj, meanB, N);
        k_gemm1<<<ggrid, 256, 0, stream>>>(meanB, xbf, flags, W1p, bias1, d_out, xemb, N);
        k_agg<unsigned short><<<agrid, 256, 0, stream>>>(xemb, rowptr, aux, deg, adj, meanB, N);
        k_gemm2<<<ggrid, 256, 0, stream>>>(meanB, xemb, W2p, bias2, flags, d_out, N);
    } else {
        int* adj = (int*)adjv;
        k_place<int><<<egrid, 256, 0, stream>>>(ei, flags, rowptr, aux, rank, adj, E, N);
        k_agg<int><<<agrid, 256, 0, stream>>>(xbf, rowptr, aux, deg, adj, meanB, N);
        k_gemm1<<<ggrid, 256, 0, stream>>>(meanB, xbf, flags, W1p, bias1, d_out, xemb, N);
        k_agg<int><<<agrid, 256, 0, stream>>>(xemb, rowptr, aux, deg, adj, meanB, N);
        k_gemm2<<<ggrid, 256, 0, stream>>>(meanB, xemb, W2p, bias2, flags, d_out, N);
    }
}

// Round 9
// 176.679 us; speedup vs baseline: 4.6149x; 1.0811x over previous
//
#include <hip/hip_runtime.h>

typedef __attribute__((__ext_vector_type__(8))) __bf16 bf16x8;
typedef __attribute__((__ext_vector_type__(4))) float f32x4;
typedef __attribute__((__ext_vector_type__(2))) float f32x2;
typedef __attribute__((__ext_vector_type__(4))) unsigned int u32x4;

__device__ __forceinline__ float bf2f(unsigned short u) {
    return __uint_as_float(((unsigned int)u) << 16);
}
__device__ __forceinline__ unsigned short f2bf(float f) {
    unsigned int u = __float_as_uint(f);
    u += 0x7FFFu + ((u >> 16) & 1u);   // RNE
    return (unsigned short)(u >> 16);
}

// ---------------------------------------------------------------------------
// Per-wave dtype probes (replace the k_detect kernel; every wave reads the
// same 64 probe words -> identical wave-uniform verdict).
// ---------------------------------------------------------------------------
__device__ __forceinline__ bool low_short_is_bf16like(unsigned int w) {
    unsigned int lo = w & 0xFFFFu;
    if (lo == 0u || lo == 0x8000u) return true;
    unsigned int e = (lo >> 7) & 0xFFu;
    return (e >= 0x6Cu && e <= 0x8Cu);
}
__device__ __forceinline__ int probe_f32(const unsigned int* __restrict__ p) {
    int t = threadIdx.x & 63;
    int cnt = __popcll(__ballot(low_short_is_bf16like(p[t])));
    return (cnt < 32) ? 1 : 0;          // few bf16-like low-shorts -> fp32
}
__device__ __forceinline__ int probe_e64(const unsigned int* __restrict__ ei) {
    int t = threadIdx.x & 63;
    unsigned int o1 = ei[2 * t + 1];
    unsigned int o2 = ei[2 * t + 129];
    return __all((o1 == 0u) && (o2 == 0u)) ? 1 : 0;
}

// ---------------------------------------------------------------------------
// x -> xbf (bf16) + x8 (fp8 e4m3); tail blocks clear deg.
// ---------------------------------------------------------------------------
__global__ __launch_bounds__(256) void k_tobf(
    const void* __restrict__ xv, unsigned short* __restrict__ xbf,
    unsigned int* __restrict__ x8, int* __restrict__ deg,
    long nelem, int n, int tgrid)
{
    if ((int)blockIdx.x >= tgrid) {
        int j = ((int)blockIdx.x - tgrid) * 256 + threadIdx.x;
        if (j < n) deg[j] = 0;
        return;
    }
    int xf32 = probe_f32((const unsigned int*)xv);
    long i = ((long)blockIdx.x * 256 + threadIdx.x) * 8;
    if (i >= nelem) return;
    float f[8];
    if (xf32) {
        const float4* p = (const float4*)((const float*)xv + i);
        float4 v0 = p[0], v1 = p[1];
        f[0] = v0.x; f[1] = v0.y; f[2] = v0.z; f[3] = v0.w;
        f[4] = v1.x; f[5] = v1.y; f[6] = v1.z; f[7] = v1.w;
        u32x4 o;
        o.x = (unsigned int)f2bf(f[0]) | ((unsigned int)f2bf(f[1]) << 16);
        o.y = (unsigned int)f2bf(f[2]) | ((unsigned int)f2bf(f[3]) << 16);
        o.z = (unsigned int)f2bf(f[4]) | ((unsigned int)f2bf(f[5]) << 16);
        o.w = (unsigned int)f2bf(f[6]) | ((unsigned int)f2bf(f[7]) << 16);
        *(u32x4*)&xbf[i] = o;
    } else {
        u32x4 v = *(const u32x4*)((const unsigned short*)xv + i);
        *(u32x4*)&xbf[i] = v;
        f[0] = bf2f((unsigned short)v.x); f[1] = bf2f((unsigned short)(v.x >> 16));
        f[2] = bf2f((unsigned short)v.y); f[3] = bf2f((unsigned short)(v.y >> 16));
        f[4] = bf2f((unsigned short)v.z); f[5] = bf2f((unsigned short)(v.z >> 16));
        f[6] = bf2f((unsigned short)v.w); f[7] = bf2f((unsigned short)(v.w >> 16));
    }
    unsigned int q0 = 0, q1 = 0;
    q0 = (unsigned int)__builtin_amdgcn_cvt_pk_fp8_f32(f[0], f[1], (int)q0, false);
    q0 = (unsigned int)__builtin_amdgcn_cvt_pk_fp8_f32(f[2], f[3], (int)q0, true);
    q1 = (unsigned int)__builtin_amdgcn_cvt_pk_fp8_f32(f[4], f[5], (int)q1, false);
    q1 = (unsigned int)__builtin_amdgcn_cvt_pk_fp8_f32(f[6], f[7], (int)q1, true);
    uint2 q; q.x = q0; q.y = q1;
    *(uint2*)&x8[i >> 2] = q;            // byte offset i
}

// ---------------------------------------------------------------------------
// xemb (bf16) -> xemb8 (fp8).
// ---------------------------------------------------------------------------
__global__ __launch_bounds__(256) void k_to8(
    const unsigned short* __restrict__ src, unsigned int* __restrict__ dst,
    long nelem)
{
    long i = ((long)blockIdx.x * 256 + threadIdx.x) * 8;
    if (i >= nelem) return;
    u32x4 v = *(const u32x4*)&src[i];
    unsigned int q0 = 0, q1 = 0;
    q0 = (unsigned int)__builtin_amdgcn_cvt_pk_fp8_f32(
            bf2f((unsigned short)v.x), bf2f((unsigned short)(v.x >> 16)), (int)q0, false);
    q0 = (unsigned int)__builtin_amdgcn_cvt_pk_fp8_f32(
            bf2f((unsigned short)v.y), bf2f((unsigned short)(v.y >> 16)), (int)q0, true);
    q1 = (unsigned int)__builtin_amdgcn_cvt_pk_fp8_f32(
            bf2f((unsigned short)v.z), bf2f((unsigned short)(v.z >> 16)), (int)q1, false);
    q1 = (unsigned int)__builtin_amdgcn_cvt_pk_fp8_f32(
            bf2f((unsigned short)v.w), bf2f((unsigned short)(v.w >> 16)), (int)q1, true);
    uint2 q; q.x = q0; q.y = q1;
    *(uint2*)&dst[i >> 2] = q;
}

// ---------------------------------------------------------------------------
// Merged weight folding: blocks [0,128) -> W1p, [128,448) -> W2p, 448 -> biases.
// ---------------------------------------------------------------------------
__global__ __launch_bounds__(256) void k_fold(
    const void* __restrict__ Wl, const void* __restrict__ Wr,
    const void* __restrict__ Wsk, const void* __restrict__ gamma,
    const void* __restrict__ rvar, const void* __restrict__ bl,
    const void* __restrict__ bsk, const void* __restrict__ rmean,
    const void* __restrict__ beta, const void* __restrict__ Wlo,
    const void* __restrict__ blo, const void* __restrict__ Wro,
    unsigned short* __restrict__ W1p, unsigned short* __restrict__ W2p,
    float* __restrict__ bias1, float* __restrict__ bias2)
{
    int wf32 = probe_f32((const unsigned int*)Wl);
    int b = blockIdx.x, t = threadIdx.x;
    if (b < 128) {
        int idx = b * 256 + t;
        int kb = idx >> 10, c = (idx >> 3) & 127, k7 = idx & 7;
        int k = kb * 8 + k7;
        float g, rv, w;
        if (wf32) {
            g  = ((const float*)gamma)[c];
            rv = ((const float*)rvar)[c];
            if (k < 128) w = ((const float*)Wl)[k * 128 + c];
            else { int kk = k - 128;
                   w = ((const float*)Wr)[kk * 128 + c] + ((const float*)Wsk)[kk * 128 + c]; }
        } else {
            g  = bf2f(((const unsigned short*)gamma)[c]);
            rv = bf2f(((const unsigned short*)rvar)[c]);
            if (k < 128) w = bf2f(((const unsigned short*)Wl)[k * 128 + c]);
            else { int kk = k - 128;
                   w = bf2f(((const unsigned short*)Wr)[kk * 128 + c]) +
                       bf2f(((const unsigned short*)Wsk)[kk * 128 + c]); }
        }
        float s = g * rsqrtf(rv + 1e-5f);
        W1p[idx] = f2bf(w * s);
    } else if (b < 448) {
        int idx = (b - 128) * 256 + t;
        int kb = idx / 2560;
        int rem = idx - kb * 2560;
        int c = rem >> 3, k7 = idx & 7;
        int k = kb * 8 + k7;
        float w = 0.f;
        if (c < 300) {
            if (wf32)
                w = (k < 128) ? ((const float*)Wlo)[k * 300 + c]
                              : ((const float*)Wro)[(k - 128) * 300 + c];
            else
                w = (k < 128) ? bf2f(((const unsigned short*)Wlo)[k * 300 + c])
                              : bf2f(((const unsigned short*)Wro)[(k - 128) * 300 + c]);
        }
        W2p[idx] = f2bf(w);
    } else {
        if (t < 128) {
            float g, rv, b1, b2, rm, be;
            if (wf32) {
                g = ((const float*)gamma)[t]; rv = ((const float*)rvar)[t];
                b1 = ((const float*)bl)[t];   b2 = ((const float*)bsk)[t];
                rm = ((const float*)rmean)[t]; be = ((const float*)beta)[t];
            } else {
                g = bf2f(((const unsigned short*)gamma)[t]); rv = bf2f(((const unsigned short*)rvar)[t]);
                b1 = bf2f(((const unsigned short*)bl)[t]);   b2 = bf2f(((const unsigned short*)bsk)[t]);
                rm = bf2f(((const unsigned short*)rmean)[t]); be = bf2f(((const unsigned short*)beta)[t]);
            }
            float s = g * rsqrtf(rv + 1e-5f);
            bias1[t] = (b1 + b2 - rm) * s + be;
        }
        for (int c = t; c < 320; c += 256) {
            float v = 0.f;
            if (c < 300)
                v = wf32 ? ((const float*)blo)[c] : bf2f(((const unsigned short*)blo)[c]);
            bias2[c] = v;
        }
    }
}

// ---------------------------------------------------------------------------
// CSR build, single atomic pass (validated round 6-8).
// ---------------------------------------------------------------------------
__global__ __launch_bounds__(256) void k_rank(
    const int* __restrict__ ei,
    int* __restrict__ deg, int* __restrict__ rank, int E, int nnodes)
{
    int e64 = probe_e64((const unsigned int*)ei);
    int e = blockIdx.x * 256 + threadIdx.x;
    if (e >= E) return;
    int d = e64 ? ei[2 * (E + e)] : ei[E + e];
    int r = 0;
    if ((unsigned)d < (unsigned)nnodes) r = atomicAdd(&deg[d], 1);
    rank[e] = r;
}

template <typename IT>
__global__ __launch_bounds__(256) void k_place(
    const int* __restrict__ ei,
    const int* __restrict__ rowptr, const int* __restrict__ aux,
    const int* __restrict__ rank,
    IT* __restrict__ adj, int E, int nnodes)
{
    int e64 = probe_e64((const unsigned int*)ei);
    int e = blockIdx.x * 256 + threadIdx.x;
    if (e >= E) return;
    int s, d;
    if (e64) { s = ei[2 * e]; d = ei[2 * (E + e)]; }
    else     { s = ei[e];     d = ei[E + e]; }
    if ((unsigned)d >= (unsigned)nnodes) return;
    if ((unsigned)s >= (unsigned)nnodes) s = 0;
    adj[rowptr[d] + aux[d >> 10] + rank[e]] = (IT)s;
}

__global__ __launch_bounds__(256) void k_scan_a(
    const int* __restrict__ deg, int* __restrict__ rowptr,
    int* __restrict__ aux, int n)
{
    __shared__ int wsum[4];
    int t = threadIdx.x, blk = blockIdx.x;
    int base = blk * 1024 + t * 4;
    int v[4];
    int s = 0;
    #pragma unroll
    for (int i = 0; i < 4; i++) { int idx = base + i; v[i] = (idx < n) ? deg[idx] : 0; s += v[i]; }
    int lane = t & 63, wv = t >> 6;
    int inc = s;
    #pragma unroll
    for (int off = 1; off < 64; off <<= 1) {
        int u = __shfl_up(inc, off);
        if (lane >= off) inc += u;
    }
    if (lane == 63) wsum[wv] = inc;
    __syncthreads();
    int woff = 0;
    if (wv >= 1) woff += wsum[0];
    if (wv >= 2) woff += wsum[1];
    if (wv >= 3) woff += wsum[2];
    int exc = woff + inc - s;
    #pragma unroll
    for (int i = 0; i < 4; i++) { int idx = base + i; if (idx < n) rowptr[idx] = exc; exc += v[i]; }
    if (t == 255) aux[blk] = woff + inc;
}

__global__ __launch_bounds__(64) void k_scan_b(int* __restrict__ aux, int nblk)
{
    int t = threadIdx.x;
    int carry = 0;
    for (int base = 0; base < nblk; base += 64) {
        int idx = base + t;
        int v = (idx < nblk) ? aux[idx] : 0;
        int inc = v;
        #pragma unroll
        for (int off = 1; off < 64; off <<= 1) {
            int u = __shfl_up(inc, off);
            if (t >= off) inc += u;
        }
        if (idx < nblk) aux[idx] = carry + inc - v;   // exclusive
        carry += __shfl(inc, 63);
    }
}

// ---------------------------------------------------------------------------
// Gather-mean over fp8 rows (128B/row): one wave per dst node. 32 sublanes
// own 4 channels each (one uint load); half-waves take alternating edges of
// the same node; 4-deep unroll per half = 8 edges in flight per wave.
// HW decode via v_cvt_pk_f32_fp8. Mean written bf16.
// ---------------------------------------------------------------------------
template <typename IT>
__global__ __launch_bounds__(256) void k_agg(
    const unsigned int* __restrict__ x8,
    const int* __restrict__ rowptr, const int* __restrict__ aux,
    const int* __restrict__ deg,
    const IT* __restrict__ adj, unsigned short* __restrict__ meanB, int n)
{
    int wid = (blockIdx.x * 256 + threadIdx.x) >> 6;   // node id
    if (wid >= n) return;
    int lane = threadIdx.x & 63;
    int h  = lane >> 5;
    int sl = lane & 31;
    int start = rowptr[wid] + aux[wid >> 10];
    int dc = deg[wid];
    float acc[4][4];
    #pragma unroll
    for (int u = 0; u < 4; u++)
        #pragma unroll
        for (int c = 0; c < 4; c++) acc[u][c] = 0.f;
    int i = 0;
    for (; i + 7 < dc; i += 8) {
        int e0 = (int)adj[start + i + h];
        int e1 = (int)adj[start + i + 2 + h];
        int e2 = (int)adj[start + i + 4 + h];
        int e3 = (int)adj[start + i + 6 + h];
        unsigned int p0 = x8[(size_t)e0 * 32 + sl];
        unsigned int p1 = x8[(size_t)e1 * 32 + sl];
        unsigned int p2 = x8[(size_t)e2 * 32 + sl];
        unsigned int p3 = x8[(size_t)e3 * 32 + sl];
        f32x2 l0 = __builtin_amdgcn_cvt_pk_f32_fp8((int)p0, false);
        f32x2 h0 = __builtin_amdgcn_cvt_pk_f32_fp8((int)p0, true);
        f32x2 l1 = __builtin_amdgcn_cvt_pk_f32_fp8((int)p1, false);
        f32x2 h1 = __builtin_amdgcn_cvt_pk_f32_fp8((int)p1, true);
        f32x2 l2 = __builtin_amdgcn_cvt_pk_f32_fp8((int)p2, false);
        f32x2 h2 = __builtin_amdgcn_cvt_pk_f32_fp8((int)p2, true);
        f32x2 l3 = __builtin_amdgcn_cvt_pk_f32_fp8((int)p3, false);
        f32x2 h3 = __builtin_amdgcn_cvt_pk_f32_fp8((int)p3, true);
        acc[0][0] += l0.x; acc[0][1] += l0.y; acc[0][2] += h0.x; acc[0][3] += h0.y;
        acc[1][0] += l1.x; acc[1][1] += l1.y; acc[1][2] += h1.x; acc[1][3] += h1.y;
        acc[2][0] += l2.x; acc[2][1] += l2.y; acc[2][2] += h2.x; acc[2][3] += h2.y;
        acc[3][0] += l3.x; acc[3][1] += l3.y; acc[3][2] += h3.x; acc[3][3] += h3.y;
    }
    for (; i + h < dc; i += 2) {
        int e0 = (int)adj[start + i + h];
        unsigned int p0 = x8[(size_t)e0 * 32 + sl];
        f32x2 l0 = __builtin_amdgcn_cvt_pk_f32_fp8((int)p0, false);
        f32x2 h0 = __builtin_amdgcn_cvt_pk_f32_fp8((int)p0, true);
        acc[0][0] += l0.x; acc[0][1] += l0.y; acc[0][2] += h0.x; acc[0][3] += h0.y;
    }
    float t0 = (acc[0][0] + acc[1][0]) + (acc[2][0] + acc[3][0]);
    float t1 = (acc[0][1] + acc[1][1]) + (acc[2][1] + acc[3][1]);
    float t2 = (acc[0][2] + acc[1][2]) + (acc[2][2] + acc[3][2]);
    float t3 = (acc[0][3] + acc[1][3]) + (acc[2][3] + acc[3][3]);
    t0 += __shfl_xor(t0, 32);
    t1 += __shfl_xor(t1, 32);
    t2 += __shfl_xor(t2, 32);
    t3 += __shfl_xor(t3, 32);
    if (h == 0) {
        float inv = 1.f / fmaxf((float)dc, 1.f);
        uint2 o;
        o.x = (unsigned int)f2bf(t0 * inv) | ((unsigned int)f2bf(t1 * inv) << 16);
        o.y = (unsigned int)f2bf(t2 * inv) | ((unsigned int)f2bf(t3 * inv) << 16);
        *(uint2*)&meanB[(size_t)wid * 128 + sl * 4] = o;
    }
}

// ---------------------------------------------------------------------------
// GEMM1: h = [mean | xbf] (32x256 tile) @ W1p (256x128) + bias1.
// ---------------------------------------------------------------------------
__global__ __launch_bounds__(256) void k_gemm1(
    const unsigned short* __restrict__ meanB,
    const unsigned short* __restrict__ xbf, const unsigned int* __restrict__ xprobe,
    const unsigned short* __restrict__ Wp,
    const float* __restrict__ bias, void* __restrict__ outh,
    unsigned short* __restrict__ xemb, int nrows)
{
    constexpr int NTW = 2;
    __shared__ __align__(16) unsigned short Alds[32 * 264];
    int tid = threadIdx.x;
    int row0 = blockIdx.x * 32;
    int xf32 = probe_f32(xprobe);
    {
        int r = tid >> 3, c0 = (tid & 7) * 16;
        int rg = row0 + r; if (rg >= nrows) rg = nrows - 1;
        const u32x4* mp = (const u32x4*)(meanB + (size_t)rg * 128 + c0);
        *(u32x4*)&Alds[r * 264 + c0]     = mp[0];
        *(u32x4*)&Alds[r * 264 + c0 + 8] = mp[1];
        const u32x4* xp = (const u32x4*)(xbf + (size_t)rg * 128 + c0);
        *(u32x4*)&Alds[r * 264 + 128 + c0]     = xp[0];
        *(u32x4*)&Alds[r * 264 + 128 + c0 + 8] = xp[1];
    }
    __syncthreads();
    f32x4 acc[2][NTW];
    #pragma unroll
    for (int a = 0; a < 2; a++)
        #pragma unroll
        for (int b = 0; b < NTW; b++) acc[a][b] = f32x4{0.f, 0.f, 0.f, 0.f};
    int lane = tid & 63, wv = tid >> 6, lh = lane & 15, lq = lane >> 4;
    #pragma unroll
    for (int ks = 0; ks < 8; ++ks) {
        bf16x8 a0 = *(const bf16x8*)&Alds[lh * 264 + ks * 32 + lq * 8];
        bf16x8 a1 = *(const bf16x8*)&Alds[(16 + lh) * 264 + ks * 32 + lq * 8];
        #pragma unroll
        for (int i = 0; i < NTW; i++) {
            int col = (wv + 4 * i) * 16 + lh;
            bf16x8 bfr = *(const bf16x8*)&Wp[(ks * 4 + lq) * 1024 + col * 8];
            acc[0][i] = __builtin_amdgcn_mfma_f32_16x16x32_bf16(a0, bfr, acc[0][i], 0, 0, 0);
            acc[1][i] = __builtin_amdgcn_mfma_f32_16x16x32_bf16(a1, bfr, acc[1][i], 0, 0, 0);
        }
    }
    float* outF = (float*)outh;
    unsigned short* outB = (unsigned short*)outh;
    #pragma unroll
    for (int rt = 0; rt < 2; ++rt)
        #pragma unroll
        for (int i = 0; i < NTW; i++)
            #pragma unroll
            for (int j = 0; j < 4; j++) {
                int r = row0 + rt * 16 + lq * 4 + j;
                if (r < nrows) {
                    int c = (wv + 4 * i) * 16 + lh;
                    float v = acc[rt][i][j] + bias[c];
                    if (xf32) outF[(size_t)r * 128 + c] = v;
                    else      outB[(size_t)r * 128 + c] = f2bf(v);
                    xemb[(size_t)r * 128 + c] = f2bf(fmaxf(v, 0.f));
                }
            }
}

// ---------------------------------------------------------------------------
// GEMM2 + fused log_softmax, register-space epilogue (validated round 7-8).
// ---------------------------------------------------------------------------
__global__ __launch_bounds__(256) void k_gemm2(
    const unsigned short* __restrict__ meanB,
    const unsigned short* __restrict__ xf, const unsigned int* __restrict__ xprobe,
    const unsigned short* __restrict__ Wp,
    const float* __restrict__ bias, void* __restrict__ outbase, int nrows)
{
    constexpr int NTW = 5;
    __shared__ __align__(16) unsigned short Alds[32 * 264];
    __shared__ float redM[4][32];
    __shared__ float redS[4][32];
    int tid = threadIdx.x;
    int row0 = blockIdx.x * 32;
    int xf32 = probe_f32(xprobe);
    {
        int r = tid >> 3, c0 = (tid & 7) * 16;
        int rg = row0 + r; if (rg >= nrows) rg = nrows - 1;
        const u32x4* mp = (const u32x4*)(meanB + (size_t)rg * 128 + c0);
        *(u32x4*)&Alds[r * 264 + c0]     = mp[0];
        *(u32x4*)&Alds[r * 264 + c0 + 8] = mp[1];
        const u32x4* xp = (const u32x4*)(xf + (size_t)rg * 128 + c0);
        *(u32x4*)&Alds[r * 264 + 128 + c0]     = xp[0];
        *(u32x4*)&Alds[r * 264 + 128 + c0 + 8] = xp[1];
    }
    __syncthreads();
    f32x4 acc[2][NTW];
    #pragma unroll
    for (int a = 0; a < 2; a++)
        #pragma unroll
        for (int b = 0; b < NTW; b++) acc[a][b] = f32x4{0.f, 0.f, 0.f, 0.f};
    int lane = tid & 63, wv = tid >> 6, lh = lane & 15, lq = lane >> 4;
    #pragma unroll
    for (int ks = 0; ks < 8; ++ks) {
        bf16x8 a0 = *(const bf16x8*)&Alds[lh * 264 + ks * 32 + lq * 8];
        bf16x8 a1 = *(const bf16x8*)&Alds[(16 + lh) * 264 + ks * 32 + lq * 8];
        #pragma unroll
        for (int i = 0; i < NTW; i++) {
            int col = (wv + 4 * i) * 16 + lh;
            bf16x8 bfr = *(const bf16x8*)&Wp[(ks * 4 + lq) * 2560 + col * 8];
            acc[0][i] = __builtin_amdgcn_mfma_f32_16x16x32_bf16(a0, bfr, acc[0][i], 0, 0, 0);
            acc[1][i] = __builtin_amdgcn_mfma_f32_16x16x32_bf16(a1, bfr, acc[1][i], 0, 0, 0);
        }
    }
    #pragma unroll
    for (int rt = 0; rt < 2; ++rt)
        #pragma unroll
        for (int i = 0; i < NTW; i++) {
            int col = (wv + 4 * i) * 16 + lh;
            float b = bias[col];
            #pragma unroll
            for (int j = 0; j < 4; j++) acc[rt][i][j] += b;
        }
    float M[2][4];
    #pragma unroll
    for (int rt = 0; rt < 2; ++rt)
        #pragma unroll
        for (int j = 0; j < 4; j++) {
            float m = -3.0e38f;
            #pragma unroll
            for (int i = 0; i < NTW; i++) {
                int col = (wv + 4 * i) * 16 + lh;
                if (col < 300) m = fmaxf(m, acc[rt][i][j]);
            }
            m = fmaxf(m, __shfl_xor(m, 1, 16));
            m = fmaxf(m, __shfl_xor(m, 2, 16));
            m = fmaxf(m, __shfl_xor(m, 4, 16));
            m = fmaxf(m, __shfl_xor(m, 8, 16));
            M[rt][j] = m;
        }
    if (lh == 0) {
        #pragma unroll
        for (int rt = 0; rt < 2; ++rt)
            #pragma unroll
            for (int j = 0; j < 4; j++)
                redM[wv][rt * 16 + lq * 4 + j] = M[rt][j];
    }
    __syncthreads();
    #pragma unroll
    for (int rt = 0; rt < 2; ++rt)
        #pragma unroll
        for (int j = 0; j < 4; j++) {
            int rl = rt * 16 + lq * 4 + j;
            M[rt][j] = fmaxf(fmaxf(redM[0][rl], redM[1][rl]),
                             fmaxf(redM[2][rl], redM[3][rl]));
        }
    float S[2][4];
    #pragma unroll
    for (int rt = 0; rt < 2; ++rt)
        #pragma unroll
        for (int j = 0; j < 4; j++) {
            float s = 0.f;
            #pragma unroll
            for (int i = 0; i < NTW; i++) {
                int col = (wv + 4 * i) * 16 + lh;
                if (col < 300) s += __expf(acc[rt][i][j] - M[rt][j]);
            }
            s += __shfl_xor(s, 1, 16);
            s += __shfl_xor(s, 2, 16);
            s += __shfl_xor(s, 4, 16);
            s += __shfl_xor(s, 8, 16);
            S[rt][j] = s;
        }
    if (lh == 0) {
        #pragma unroll
        for (int rt = 0; rt < 2; ++rt)
            #pragma unroll
            for (int j = 0; j < 4; j++)
                redS[wv][rt * 16 + lq * 4 + j] = S[rt][j];
    }
    __syncthreads();
    float* out1F = (float*)outbase + (size_t)nrows * 128;
    unsigned short* out1B = (unsigned short*)outbase + (size_t)nrows * 128;
    #pragma unroll
    for (int rt = 0; rt < 2; ++rt)
        #pragma unroll
        for (int j = 0; j < 4; j++) {
            int rl = rt * 16 + lq * 4 + j;
            float Sall = (redS[0][rl] + redS[1][rl]) + (redS[2][rl] + redS[3][rl]);
            float L = M[rt][j] + __logf(Sall);
            int rg = row0 + rl;
            if (rg < nrows) {
                #pragma unroll
                for (int i = 0; i < NTW; i++) {
                    int col = (wv + 4 * i) * 16 + lh;
                    if (col < 300) {
                        float v = acc[rt][i][j] - L;
                        if (xf32) out1F[(size_t)rg * 300 + col] = v;
                        else      out1B[(size_t)rg * 300 + col] = f2bf(v);
                    }
                }
            }
        }
}

// ---------------------------------------------------------------------------
extern "C" void kernel_launch(void* const* d_in, const int* in_sizes, int n_in,
                              void* d_out, int out_size, void* d_ws, size_t ws_size,
                              hipStream_t stream)
{
    const void* x     = d_in[0];
    const int*  ei    = (const int*)d_in[1];
    const void* Wl    = d_in[2];
    const void* bl    = d_in[3];
    const void* Wr    = d_in[4];
    const void* Wsk   = d_in[5];
    const void* bsk   = d_in[6];
    const void* gamma = d_in[7];
    const void* beta  = d_in[8];
    const void* rmean = d_in[9];
    const void* rvar  = d_in[10];
    const void* Wlo   = d_in[11];
    const void* blo   = d_in[12];
    const void* Wro   = d_in[13];

    int N = in_sizes[0] / 128;
    int E = in_sizes[1] / 2;
    long nelem = (long)N * 128;
    bool idx16 = (N <= 65535);

    char* ws = (char*)d_ws;
    size_t off = 0;
    unsigned short* xbf   = (unsigned short*)(ws + off); off += (size_t)N * 128 * 2;
    unsigned short* meanB = (unsigned short*)(ws + off); off += (size_t)N * 128 * 2;
    unsigned short* xemb  = (unsigned short*)(ws + off); off += (size_t)N * 128 * 2;
    unsigned int* x8      = (unsigned int*)(ws + off);   off += (size_t)N * 128;
    unsigned int* xemb8   = (unsigned int*)(ws + off);   off += (size_t)N * 128;
    off = (off + 255) & ~(size_t)255;
    int* deg    = (int*)(ws + off);           off += (size_t)N * 4;
    int* rowptr = (int*)(ws + off);           off += (size_t)N * 4;
    int* rank   = (int*)(ws + off);           off += (size_t)E * 4;
    int* aux    = (int*)(ws + off);           off += 256;
    void* adjv  = (void*)(ws + off);          off += (size_t)E * 4;   // u16 uses half
    off = (off + 255) & ~(size_t)255;
    unsigned short* W1p = (unsigned short*)(ws + off);  off += 32768 * 2;
    unsigned short* W2p = (unsigned short*)(ws + off);  off += 81920 * 2;
    float* bias1 = (float*)(ws + off);        off += 512;
    float* bias2 = (float*)(ws + off);        off += 1280;

    int egrid = (E + 255) / 256;
    int sblk  = (N + 1023) / 1024;
    int agrid = (N + 3) / 4;
    int ggrid = (N + 31) / 32;
    int tgrid = (int)((nelem / 8 + 255) / 256);
    int dgrid = (N + 255) / 256;

    const unsigned int* xprobe = (const unsigned int*)x;

    // setup: convert x (bf16 + fp8), clear deg, fold weights
    k_tobf<<<tgrid + dgrid, 256, 0, stream>>>(x, xbf, x8, deg, nelem, N, tgrid);
    k_fold<<<449, 256, 0, stream>>>(Wl, Wr, Wsk, gamma, rvar, bl, bsk, rmean, beta,
                                    Wlo, blo, Wro, W1p, W2p, bias1, bias2);

    // CSR build
    k_rank<<<egrid, 256, 0, stream>>>(ei, deg, rank, E, N);
    k_scan_a<<<sblk, 256, 0, stream>>>(deg, rowptr, aux, N);
    k_scan_b<<<1, 64, 0, stream>>>(aux, sblk);

    if (idx16) {
        unsigned short* adj = (unsigned short*)adjv;
        k_place<unsigned short><<<egrid, 256, 0, stream>>>(ei, rowptr, aux, rank, adj, E, N);
        k_agg<unsigned short><<<agrid, 256, 0, stream>>>(x8, rowptr, aux, deg, adj, meanB, N);
        k_gemm1<<<ggrid, 256, 0, stream>>>(meanB, xbf, xprobe, W1p, bias1, d_out, xemb, N);
        k_to8<<<tgrid, 256, 0, stream>>>(xemb, xemb8, nelem);
        k_agg<unsigned short><<<agrid, 256, 0, stream>>>(xemb8, rowptr, aux, deg, adj, meanB, N);
        k_gemm2<<<ggrid, 256, 0, stream>>>(meanB, xemb, xprobe, W2p, bias2, d_out, N);
    } else {
        int* adj = (int*)adjv;
        k_place<int><<<egrid, 256, 0, stream>>>(ei, rowptr, aux, rank, adj, E, N);
        k_agg<int><<<agrid, 256, 0, stream>>>(x8, rowptr, aux, deg, adj, meanB, N);
        k_gemm1<<<ggrid, 256, 0, stream>>>(meanB, xbf, xprobe, W1p, bias1, d_out, xemb, N);
        k_to8<<<tgrid, 256, 0, stream>>>(xemb, xemb8, nelem);
        k_agg<int><<<agrid, 256, 0, stream>>>(xemb8, rowptr, aux, deg, adj, meanB, N);
        k_gemm2<<<ggrid, 256, 0, stream>>>(meanB, xemb, xprobe, W2p, bias2, d_out, N);
    }
}